// Round 1
// baseline (1108.897 us; speedup 1.0000x reference)
//
#include <hip/hip_runtime.h>
#include <math.h>

// LeNet-5 fused forward, fp32, one workgroup (256 thr) per image.
// ws layout (floats): [0..216) k1 folded 6x6x6, [216..222) b1,
//                     [224..3680) k3 folded 16x6x6x6 (masked), [3680..3696) b3

// MAP_INFO columns packed as 6-bit masks: bit i of MASK16[o] = MAP_INFO[i][o]
__device__ const unsigned char MASK16[16] = {7,14,28,56,49,35,15,30,60,57,51,39,27,54,45,63};

__device__ __forceinline__ float squash(float x) {
    // 1.7159 * tanh(2x/3), tanh via fast exp: tanh(z)=sign(z)*(1-e)/(1+e), e=exp(-2|z|)
    float z = (2.0f / 3.0f) * x;
    float a = fabsf(z);
    float e = __expf(-2.0f * a);
    float t = (1.0f - e) * __builtin_amdgcn_rcpf(1.0f + e);
    return copysignf(1.7159f * t, z);
}

__global__ __launch_bounds__(256) void prep_kernel(
    const float* __restrict__ c1_w, const float* __restrict__ c1_b,
    const float* __restrict__ s2_w, const float* __restrict__ s2_b,
    const float* __restrict__ c3_w, const float* __restrict__ c3_b,
    const float* __restrict__ s4_w, const float* __restrict__ s4_b,
    float* __restrict__ ws)
{
    const int tid = threadIdx.x;
    // Folded C1+S2 kernel: 6x6 avg of 5x5 taps, scaled by s2_w[c]
    for (int idx = tid; idx < 216; idx += 256) {
        int c = idx / 36, r = idx - c * 36;
        int u = r / 6, v = r - u * 6;
        float s = 0.f;
        #pragma unroll
        for (int dy = 0; dy < 2; ++dy)
            #pragma unroll
            for (int dx = 0; dx < 2; ++dx) {
                int ky = u - dy, kx = v - dx;
                if (ky >= 0 && ky < 5 && kx >= 0 && kx < 5)
                    s += c1_w[(c * 5 + ky) * 5 + kx];
            }
        ws[idx] = 0.25f * s * s2_w[c];
    }
    if (tid < 6) ws[216 + tid] = s2_w[tid] * c1_b[tid] + s2_b[tid];
    // Folded C3+S4 kernel: masked by connectivity, scaled by s4_w[o]
    for (int idx = tid; idx < 3456; idx += 256) {
        int o = idx / 216, r = idx - o * 216;
        int i = r / 36, r2 = r - i * 36;
        int u = r2 / 6, v = r2 - u * 6;
        float s = 0.f;
        #pragma unroll
        for (int dy = 0; dy < 2; ++dy)
            #pragma unroll
            for (int dx = 0; dx < 2; ++dx) {
                int ky = u - dy, kx = v - dx;
                if (ky >= 0 && ky < 5 && kx >= 0 && kx < 5)
                    s += c3_w[((o * 6 + i) * 5 + ky) * 5 + kx];
            }
        float m = ((MASK16[o] >> i) & 1) ? (0.25f * s4_w[o]) : 0.f;
        ws[224 + idx] = s * m;
    }
    if (tid < 16) ws[3680 + tid] = s4_w[tid] * c3_b[tid] + s4_b[tid];
}

__global__ __launch_bounds__(256) void lenet_kernel(
    const float* __restrict__ x,
    const float* __restrict__ c5_w, const float* __restrict__ c5_b,
    const float* __restrict__ f6_w, const float* __restrict__ f6_b,
    const float* __restrict__ rbf_w,
    const float* __restrict__ ws,
    float* __restrict__ out)
{
    // s_u union: phase A/B/C: xpad[1296] + s2[6][16][18 pitch]=1728 (total 3024)
    //            phase D: c5 weight slices 2*3000=6000; phase E: f6 chunks 84*28=2352
    __shared__ __align__(16) float s_u[6016];
    __shared__ __align__(16) float s_s4[576];   // [16][6][6]
    __shared__ __align__(16) float s_c5[480];   // [120][2][2] flat c*4+s
    __shared__ __align__(16) float s_f6h[336];  // [4][84]
    __shared__ __align__(16) float s_c5b[120];
    __shared__ __align__(16) float s_f6b[84];
    __shared__ __align__(16) float s_rbf[840];  // [84][10]

    const int tid = threadIdx.x;
    const int b = blockIdx.x;
    float* s_xpad = s_u;          // [36][36]
    float* s_s2   = s_u + 1296;   // [6][16][18]
    float* s_wbuf = s_u;

    // ---- stage small constants ----
    if (tid < 120) s_c5b[tid] = c5_b[tid];
    if (tid < 84)  s_f6b[tid] = f6_b[tid];
    for (int idx = tid; idx < 210; idx += 256)
        ((float4*)s_rbf)[idx] = ((const float4*)rbf_w)[idx];

    // ---- stage input with replicate pad (36x36) ----
    const float* xb = x + (size_t)b * 1024;
    for (int idx = tid; idx < 1296; idx += 256) {
        int u = idx / 36, v = idx - u * 36;
        int sy = min(max(u - 2, 0), 31);
        int sx = min(max(v - 2, 0), 31);
        s_xpad[idx] = xb[sy * 32 + sx];
    }
    __syncthreads();

    // ---- Phase B: C1+S2+act -> s_s2[6][16][18] ----
    {
        int py = tid >> 4, px = tid & 15;
        const float* base = s_xpad + py * 72 + px * 2;
        float win[36];
        #pragma unroll
        for (int u = 0; u < 6; ++u)
            #pragma unroll
            for (int v2 = 0; v2 < 3; ++v2)
                ((float2*)(win + u * 6))[v2] = ((const float2*)(base + u * 36))[v2];
        #pragma unroll
        for (int c = 0; c < 6; ++c) {
            float acc = ws[216 + c];             // wave-uniform -> s_load
            #pragma unroll
            for (int j = 0; j < 36; ++j)
                acc += win[j] * ws[c * 36 + j];  // wave-uniform weights -> SGPR
            s_s2[c * 288 + py * 18 + px] = squash(acc);
        }
    }
    __syncthreads();

    // ---- Phase C: C3+S4+act -> s_s4[16][36]; wave w owns o = {w, w+4, w+8, w+12} ----
    {
        int wave = __builtin_amdgcn_readfirstlane(tid >> 6);
        int lane = tid & 63;
        int pl = (lane < 36) ? lane : 0;
        int py = pl / 6, px = pl - py * 6;
        float acc[4] = {0.f, 0.f, 0.f, 0.f};
        #pragma unroll
        for (int i = 0; i < 6; ++i) {
            const float* sb = s_s2 + i * 288 + py * 36 + px * 2;
            float win[36];
            #pragma unroll
            for (int u = 0; u < 6; ++u)
                #pragma unroll
                for (int v2 = 0; v2 < 3; ++v2)
                    ((float2*)(win + u * 6))[v2] = ((const float2*)(sb + u * 18))[v2];
            #pragma unroll
            for (int oi = 0; oi < 4; ++oi) {
                int o = oi * 4 + wave;                       // wave-uniform
                const float* kk = ws + 224 + (o * 6 + i) * 36; // SGPR base -> s_loads
                float s = 0.f;
                #pragma unroll
                for (int j = 0; j < 36; ++j) s += win[j] * kk[j];
                acc[oi] += s;
            }
        }
        if (lane < 36) {
            #pragma unroll
            for (int oi = 0; oi < 4; ++oi) {
                int o = oi * 4 + wave;
                s_s4[o * 36 + pl] = squash(acc[oi] + ws[3680 + o]);
            }
        }
    }
    __syncthreads();

    // ---- Phase D: C5 (no act) -> s_c5[480]; thread pair (c, i-half), 4 spatial accs ----
    {
        const int cD = tid >> 1;        // 0..127, valid < 120
        const int hD = tid & 1;
        const bool actD = (cD < 120);
        float a0 = 0.f, a1 = 0.f, a2 = 0.f, a3 = 0.f;
        for (int ii = 0; ii < 8; ++ii) {
            // stage slices i=ii (half 0) and i=8+ii (half 1): 2*120*25 floats
            for (int idx = tid; idx < 6000; idx += 256) {
                int h = (idx >= 3000) ? 1 : 0;
                int r = idx - h * 3000;
                int c = r / 25, t = r - c * 25;
                s_wbuf[idx] = c5_w[c * 400 + (h * 8 + ii) * 25 + t];
            }
            __syncthreads();
            if (actD) {
                int i = hD * 8 + ii;
                const float* s4i = s_s4 + i * 36;
                float win[36];
                #pragma unroll
                for (int j = 0; j < 9; ++j)
                    ((float4*)win)[j] = ((const float4*)s4i)[j];  // broadcast, 2 addrs/wave
                const float* w = s_wbuf + hD * 3000 + cD * 25;
                #pragma unroll
                for (int ky = 0; ky < 5; ++ky)
                    #pragma unroll
                    for (int kx = 0; kx < 5; ++kx) {
                        float wv = w[ky * 5 + kx];
                        a0 += win[ky * 6 + kx]           * wv;  // s=0 (y0,x0)
                        a1 += win[ky * 6 + kx + 1]       * wv;  // s=1 (y0,x1)
                        a2 += win[(ky + 1) * 6 + kx]     * wv;  // s=2 (y1,x0)
                        a3 += win[(ky + 1) * 6 + kx + 1] * wv;  // s=3 (y1,x1)
                    }
            }
            __syncthreads();
        }
        a0 += __shfl_xor(a0, 1);
        a1 += __shfl_xor(a1, 1);
        a2 += __shfl_xor(a2, 1);
        a3 += __shfl_xor(a3, 1);
        if (actD && hD == 0) {
            float bias = s_c5b[cD];
            s_c5[cD * 4 + 0] = a0 + bias;
            s_c5[cD * 4 + 1] = a1 + bias;
            s_c5[cD * 4 + 2] = a2 + bias;
            s_c5[cD * 4 + 3] = a3 + bias;
        }
    }
    __syncthreads();

    // ---- Phase E: F6+act -> s_f6h[4][84]; K chunked by 24, weights staged pitch 28 ----
    {
        int q0 = tid / 84, k0 = tid - q0 * 84;       // out0 = tid (always < 336)
        int i1 = tid + 256;
        int q1 = i1 / 84, k1v = i1 - q1 * 84;        // out1 valid if tid < 80
        float f0 = s_f6b[k0];
        float f1 = (tid < 80) ? s_f6b[k1v] : 0.f;
        for (int jb = 0; jb < 5; ++jb) {
            for (int idx = tid; idx < 504; idx += 256) {   // 84 rows x 6 float4
                int k = idx / 6, j4 = idx - k * 6;
                ((float4*)s_wbuf)[k * 7 + j4] = ((const float4*)f6_w)[k * 30 + jb * 6 + j4];
            }
            __syncthreads();
            {
                const float4* v0 = (const float4*)(s_c5 + q0 * 120 + jb * 24);
                const float4* w0 = (const float4*)(s_wbuf + k0 * 28);
                #pragma unroll
                for (int j = 0; j < 6; ++j) {
                    float4 a = v0[j], bb = w0[j];
                    f0 += a.x * bb.x + a.y * bb.y + a.z * bb.z + a.w * bb.w;
                }
                if (tid < 80) {
                    const float4* v1 = (const float4*)(s_c5 + q1 * 120 + jb * 24);
                    const float4* w1 = (const float4*)(s_wbuf + k1v * 28);
                    #pragma unroll
                    for (int j = 0; j < 6; ++j) {
                        float4 a = v1[j], bb = w1[j];
                        f1 += a.x * bb.x + a.y * bb.y + a.z * bb.z + a.w * bb.w;
                    }
                }
            }
            __syncthreads();
        }
        s_f6h[tid] = squash(f0);
        if (tid < 80) s_f6h[tid + 256] = squash(f1);
    }
    __syncthreads();

    // ---- Phase F: RBF distances -> out[(4b+q)*10 + cls] ----
    if (tid < 40) {
        int q = tid / 10, cls = tid - q * 10;
        const float* h = s_f6h + q * 84;
        float acc = 0.f;
        #pragma unroll
        for (int k = 0; k < 84; ++k) {
            float d = h[k] - s_rbf[k * 10 + cls];
            acc += d * d;
        }
        out[((size_t)b * 4 + q) * 10 + cls] = acc;
    }
}

extern "C" void kernel_launch(void* const* d_in, const int* in_sizes, int n_in,
                              void* d_out, int out_size, void* d_ws, size_t ws_size,
                              hipStream_t stream) {
    (void)n_in; (void)out_size; (void)ws_size;
    const float* x     = (const float*)d_in[0];
    const float* c1_w  = (const float*)d_in[1];
    const float* c1_b  = (const float*)d_in[2];
    const float* s2_w  = (const float*)d_in[3];
    const float* s2_b  = (const float*)d_in[4];
    const float* c3_w  = (const float*)d_in[5];
    const float* c3_b  = (const float*)d_in[6];
    const float* s4_w  = (const float*)d_in[7];
    const float* s4_b  = (const float*)d_in[8];
    const float* c5_w  = (const float*)d_in[9];
    const float* c5_b  = (const float*)d_in[10];
    const float* f6_w  = (const float*)d_in[11];
    const float* f6_b  = (const float*)d_in[12];
    const float* rbf_w = (const float*)d_in[13];
    float* out = (float*)d_out;
    float* ws  = (float*)d_ws;

    const int B = in_sizes[0] / 1024;  // 8192 images of 1x32x32

    prep_kernel<<<1, 256, 0, stream>>>(c1_w, c1_b, s2_w, s2_b, c3_w, c3_b, s4_w, s4_b, ws);
    lenet_kernel<<<B, 256, 0, stream>>>(x, c5_w, c5_b, f6_w, f6_b, rbf_w, ws, out);
}

// Round 2
// 647.561 us; speedup vs baseline: 1.7124x; 1.7124x over previous
//
#include <hip/hip_runtime.h>
#include <hip/hip_fp16.h>
#include <math.h>

// LeNet-5 fused forward, G=16 images per 256-thread block, 512 blocks.
// ws layout (floats): [0..216) k1 folded 6x6x6, [216..222) b1,
//   [224..3680) k3 folded 16x6x6x6 (masked), [3680..3696) b3,
//   [3696..13776) f6 weights relaid [5 chunks][84][24]

__device__ const unsigned char MASK16[16] = {7,14,28,56,49,35,15,30,60,57,51,39,27,54,45,63};

__device__ __forceinline__ float squash(float x) {
    float z = (2.0f / 3.0f) * x;
    float a = fabsf(z);
    float e = __expf(-2.0f * a);
    float t = (1.0f - e) * __builtin_amdgcn_rcpf(1.0f + e);
    return copysignf(1.7159f * t, z);
}

__global__ __launch_bounds__(256) void prep_kernel(
    const float* __restrict__ c1_w, const float* __restrict__ c1_b,
    const float* __restrict__ s2_w, const float* __restrict__ s2_b,
    const float* __restrict__ c3_w, const float* __restrict__ c3_b,
    const float* __restrict__ s4_w, const float* __restrict__ s4_b,
    const float* __restrict__ f6_w,
    float* __restrict__ ws)
{
    const int tid = threadIdx.x;
    for (int idx = tid; idx < 216; idx += 256) {
        int c = idx / 36, r = idx - c * 36;
        int u = r / 6, v = r - u * 6;
        float s = 0.f;
        #pragma unroll
        for (int dy = 0; dy < 2; ++dy)
            #pragma unroll
            for (int dx = 0; dx < 2; ++dx) {
                int ky = u - dy, kx = v - dx;
                if (ky >= 0 && ky < 5 && kx >= 0 && kx < 5)
                    s += c1_w[(c * 5 + ky) * 5 + kx];
            }
        ws[idx] = 0.25f * s * s2_w[c];
    }
    if (tid < 6) ws[216 + tid] = s2_w[tid] * c1_b[tid] + s2_b[tid];
    for (int idx = tid; idx < 3456; idx += 256) {
        int o = idx / 216, r = idx - o * 216;
        int i = r / 36, r2 = r - i * 36;
        int u = r2 / 6, v = r2 - u * 6;
        float s = 0.f;
        #pragma unroll
        for (int dy = 0; dy < 2; ++dy)
            #pragma unroll
            for (int dx = 0; dx < 2; ++dx) {
                int ky = u - dy, kx = v - dx;
                if (ky >= 0 && ky < 5 && kx >= 0 && kx < 5)
                    s += c3_w[((o * 6 + i) * 5 + ky) * 5 + kx];
            }
        float m = ((MASK16[o] >> i) & 1) ? (0.25f * s4_w[o]) : 0.f;
        ws[224 + idx] = s * m;
    }
    if (tid < 16) ws[3680 + tid] = s4_w[tid] * c3_b[tid] + s4_b[tid];
    // f6 relayout: [jc][84][24], element = f6_w[k][jc*24+t]
    for (int idx = tid; idx < 10080; idx += 256) {
        int jc = idx / 2016, r = idx - jc * 2016;
        int k = r / 24, t = r - k * 24;
        ws[3696 + idx] = f6_w[k * 120 + jc * 24 + t];
    }
}

__global__ __launch_bounds__(256) void lenet_kernel(
    const float* __restrict__ x,
    const float* __restrict__ c5_w, const float* __restrict__ c5_b,
    const float* __restrict__ f6_b,
    const float* __restrict__ rbf_w,
    const float* __restrict__ ws,
    float* __restrict__ out)
{
    // R union region (floats):
    //  B/C: xpad f32 [0..2736) (2 img, pitch 38) | s2 f16 at fl 2736 (6944 halves, 4 img, pitch 1736)
    //  E:   f6 chunk f32 [0..2352) ([84][28])    | c5 f16 at fl 2352 (7808 halves, [16][488])
    //  F:   h f32 [0..5376)  ([64][84])
    __shared__ __align__(16) float  s_R[6256];
    __shared__ __align__(16) __half s_s4[16 * 584];   // [16 img][16 ch][36], pitch 584
    __shared__ __align__(16) float  s_rbf[840];       // transposed [10][84]
    __shared__ __align__(16) float  s_f6b[84];

    const int tid  = threadIdx.x;
    const int wave = __builtin_amdgcn_readfirstlane(tid >> 6);
    const int lane = tid & 63;
    const int b16  = blockIdx.x * 16;

    // ---- stage constants ----
    for (int idx = tid; idx < 840; idx += 256) {
        int k = idx / 10, c = idx - k * 10;
        s_rbf[c * 84 + k] = rbf_w[idx];
    }
    if (tid < 84) s_f6b[tid] = f6_b[tid];

    float* xpad = s_R;
    __half* s2h = (__half*)(s_R + 2736);

    // ======== B + C: 4 sub-batches of 4 images ========
    for (int sb = 0; sb < 4; ++sb) {
        for (int hf = 0; hf < 2; ++hf) {
            __syncthreads();   // previous users of xpad / s2h done
            // stage xpad for 2 images (replicate pad, pitch 38)
            for (int idx = tid; idx < 2736; idx += 256) {
                int il = (idx >= 1368) ? 1 : 0;
                int r = idx - il * 1368;
                int u = r / 38, v = r - u * 38;
                if (v > 35) v = 35;
                int sy = min(max(u - 2, 0), 31);
                int sx = min(max(v - 2, 0), 31);
                xpad[idx] = x[(size_t)(b16 + sb * 4 + hf * 2 + il) * 1024 + sy * 32 + sx];
            }
            __syncthreads();
            // B: C1+S2+act for 2 images -> s2h (f16)
            {
                int il = tid >> 7;          // image within pair
                int p  = tid & 127;
                int imgl = hf * 2 + il;     // 0..3 in sub-batch
                for (int pp = 0; pp < 2; ++pp) {
                    int px = p + pp * 128;
                    int py = px >> 4, pxx = px & 15;
                    const float* basep = xpad + il * 1368 + (2 * py) * 38 + 2 * pxx;
                    float win[36];
                    #pragma unroll
                    for (int u = 0; u < 6; ++u) {
                        float2 a0 = *(const float2*)(basep + u * 38);
                        float2 a1 = *(const float2*)(basep + u * 38 + 2);
                        float2 a2 = *(const float2*)(basep + u * 38 + 4);
                        win[u*6+0]=a0.x; win[u*6+1]=a0.y; win[u*6+2]=a1.x;
                        win[u*6+3]=a1.y; win[u*6+4]=a2.x; win[u*6+5]=a2.y;
                    }
                    __half* s2o = s2h + imgl * 1736 + py * 18 + pxx;
                    #pragma unroll
                    for (int c = 0; c < 6; ++c) {
                        float acc = ws[216 + c];
                        #pragma unroll
                        for (int j = 0; j < 36; ++j) acc += win[j] * ws[c * 36 + j];
                        s2o[c * 288] = __float2half(squash(acc));
                    }
                }
            }
        }
        __syncthreads();
        // C: C3+S4+act for 4 images; lanes = (img,pxtri) 48 active; waves split o 4-way
        if (lane < 48) {
            int imgl = lane / 12, pxt = lane - imgl * 12;
            int img = sb * 4 + imgl;
            const __half* s2b = s2h + imgl * 1736;
            #pragma unroll
            for (int j = 0; j < 3; ++j) {
                int px = pxt + j * 12;      // 0..35
                int py = px / 6, pxx = px - py * 6;
                float accA[4] = {0.f, 0.f, 0.f, 0.f};
                for (int i = 0; i < 6; ++i) {
                    const __half* wb = s2b + i * 288 + (2 * py) * 18 + 2 * pxx;
                    float win[36];
                    #pragma unroll
                    for (int u = 0; u < 6; ++u) {
                        #pragma unroll
                        for (int vv = 0; vv < 3; ++vv) {
                            float2 f = __half22float2(*(const __half2*)(wb + u * 18 + vv * 2));
                            win[u*6+vv*2]   = f.x;
                            win[u*6+vv*2+1] = f.y;
                        }
                    }
                    #pragma unroll
                    for (int ol = 0; ol < 4; ++ol) {
                        const float* kk = ws + 224 + ((wave * 4 + ol) * 6 + i) * 36;
                        float s = 0.f;
                        #pragma unroll
                        for (int t = 0; t < 36; ++t) s += win[t] * kk[t];
                        accA[ol] += s;
                    }
                }
                #pragma unroll
                for (int ol = 0; ol < 4; ++ol) {
                    int o = wave * 4 + ol;
                    s_s4[img * 584 + o * 36 + px] = __float2half(squash(accA[ol] + ws[3680 + o]));
                }
            }
        }
    }
    __syncthreads();

    // ======== D: C5. lanes = (img,q), waves split c 30 each. SGPR weights, no barriers ========
    {
        int img = lane >> 2, q = lane & 3;
        int qy = q >> 1, qx = q & 1;
        int c0 = wave * 30;
        float acc[30];
        #pragma unroll
        for (int c = 0; c < 30; ++c) acc[c] = 0.f;
        for (int i = 0; i < 16; ++i) {
            float win[25];
            const __half* s4b = s_s4 + img * 584 + i * 36 + qy * 6 + qx;
            #pragma unroll
            for (int r = 0; r < 5; ++r)
                #pragma unroll
                for (int cc = 0; cc < 5; ++cc)
                    win[r * 5 + cc] = __half2float(s4b[r * 6 + cc]);
            const float* wrow = c5_w + (size_t)c0 * 400 + i * 25;
            #pragma unroll 2
            for (int c = 0; c < 30; ++c) {
                const float* wr = wrow + c * 400;
                float s = 0.f;
                #pragma unroll
                for (int t = 0; t < 25; ++t) s += win[t] * wr[t];
                acc[c] += s;
            }
        }
        __half* c5h = (__half*)(s_R + 2352);
        #pragma unroll
        for (int c = 0; c < 30; ++c) {
            c5h[img * 488 + q * 120 + (c0 + c)] = __float2half(acc[c] + c5_b[c0 + c]);
        }
    }
    __syncthreads();

    // ======== E: F6+act. tasks = (kp 0..41)x(rq=img 0..15), tiles 2k x 4q ========
    {
        const __half* c5h = (const __half*)(s_R + 2352);
        float* fw = s_R;   // [84][28]
        float eacc[3][2][4];
        #pragma unroll
        for (int s = 0; s < 3; ++s) {
            int t = tid + s * 256;
            if (t < 672) {
                int kp = t >> 4;
                #pragma unroll
                for (int kk = 0; kk < 2; ++kk)
                    #pragma unroll
                    for (int rr = 0; rr < 4; ++rr)
                        eacc[s][kk][rr] = s_f6b[kp * 2 + kk];
            }
        }
        for (int jc = 0; jc < 5; ++jc) {
            __syncthreads();
            for (int idx = tid; idx < 2016; idx += 256) {
                int k = idx / 24, tt = idx - k * 24;
                fw[k * 28 + tt] = ws[3696 + jc * 2016 + idx];
            }
            __syncthreads();
            #pragma unroll
            for (int s = 0; s < 3; ++s) {
                int t = tid + s * 256;
                if (t >= 672) break;
                int kp = t >> 4, rq = t & 15;
                const float* w0 = fw + (kp * 2) * 28;
                const float* w1 = w0 + 28;
                #pragma unroll
                for (int m = 0; m < 6; ++m) {
                    float4 W0 = ((const float4*)w0)[m];
                    float4 W1 = ((const float4*)w1)[m];
                    #pragma unroll
                    for (int rr = 0; rr < 4; ++rr) {
                        const __half2* vb = (const __half2*)(c5h + rq * 488 + rr * 120 + jc * 24 + m * 4);
                        float2 va  = __half22float2(vb[0]);
                        float2 vb2 = __half22float2(vb[1]);
                        eacc[s][0][rr] += va.x * W0.x + va.y * W0.y + vb2.x * W0.z + vb2.y * W0.w;
                        eacc[s][1][rr] += va.x * W1.x + va.y * W1.y + vb2.x * W1.z + vb2.y * W1.w;
                    }
                }
            }
        }
        __syncthreads();   // all E compute done before overwriting R with h
        float* hb = s_R;   // [64][84]
        #pragma unroll
        for (int s = 0; s < 3; ++s) {
            int t = tid + s * 256;
            if (t < 672) {
                int kp = t >> 4, rq = t & 15;
                #pragma unroll
                for (int rr = 0; rr < 4; ++rr)
                    #pragma unroll
                    for (int kk = 0; kk < 2; ++kk)
                        hb[(rq * 4 + rr) * 84 + kp * 2 + kk] = squash(eacc[s][kk][rr]);
            }
        }
    }
    __syncthreads();

    // ======== F: RBF -> out. task t = row*10+cls, out coalesced ========
    {
        const float* hb = s_R;
        #pragma unroll
        for (int s = 0; s < 3; ++s) {
            int t = tid + s * 256;
            if (t < 640) {
                int row = t / 10, cls = t - row * 10;
                const float* hr = hb + row * 84;
                const float* pr = s_rbf + cls * 84;
                float a = 0.f;
                #pragma unroll
                for (int m = 0; m < 21; ++m) {
                    float4 hv = ((const float4*)hr)[m];
                    float4 pv = ((const float4*)pr)[m];
                    float dx = hv.x - pv.x, dy = hv.y - pv.y;
                    float dz = hv.z - pv.z, dw = hv.w - pv.w;
                    a += dx * dx + dy * dy + dz * dz + dw * dw;
                }
                out[(size_t)blockIdx.x * 640 + t] = a;
            }
        }
    }
}

extern "C" void kernel_launch(void* const* d_in, const int* in_sizes, int n_in,
                              void* d_out, int out_size, void* d_ws, size_t ws_size,
                              hipStream_t stream) {
    (void)n_in; (void)out_size; (void)ws_size;
    const float* x     = (const float*)d_in[0];
    const float* c1_w  = (const float*)d_in[1];
    const float* c1_b  = (const float*)d_in[2];
    const float* s2_w  = (const float*)d_in[3];
    const float* s2_b  = (const float*)d_in[4];
    const float* c3_w  = (const float*)d_in[5];
    const float* c3_b  = (const float*)d_in[6];
    const float* s4_w  = (const float*)d_in[7];
    const float* s4_b  = (const float*)d_in[8];
    const float* c5_w  = (const float*)d_in[9];
    const float* c5_b  = (const float*)d_in[10];
    const float* f6_w  = (const float*)d_in[11];
    const float* f6_b  = (const float*)d_in[12];
    const float* rbf_w = (const float*)d_in[13];
    float* out = (float*)d_out;
    float* ws  = (float*)d_ws;

    const int B = in_sizes[0] / 1024;   // 8192

    prep_kernel<<<1, 256, 0, stream>>>(c1_w, c1_b, s2_w, s2_b, c3_w, c3_b,
                                       s4_w, s4_b, f6_w, ws);
    lenet_kernel<<<B / 16, 256, 0, stream>>>(x, c5_w, c5_b, f6_b, rbf_w, ws, out);
}

// Round 4
// 266.281 us; speedup vs baseline: 4.1644x; 2.4319x over previous
//
#include <hip/hip_runtime.h>
#include <math.h>

// LeNet-5 fused forward, G=8 images per 256-thread block, 1024 blocks, f16 MFMA.
typedef _Float16 h16;
typedef h16  h8v __attribute__((ext_vector_type(8)));
typedef h16  h4v __attribute__((ext_vector_type(4)));
typedef float f4v __attribute__((ext_vector_type(4)));

// ws float offsets
#define WS_K1   0       // 216 f32: folded C1+S2 6x6x6
#define WS_B1   216     // 6 f32
#define WS_B3   224     // 16 f32
#define WS_W3H  240     // 2304 f32 = [6][16][48] f16 (C3 B^T, k=u*6+v, pad 36..47=0)
#define WS_W5H  2544    // 32768 f32 = [16][128][32] f16 (C5 B^T, k=r*5+c, pads 0)
#define WS_F6H  35312   // 6144 f32 = [96][128] f16 (F6 B^T, pads 0)

// LDS byte offsets (unions; see lifetime notes)
#define L_RBF   0       // 840 f32 transposed [10][84]
#define L_B3    3360    // 16 f32
#define L_C5B   3424    // 128 f32
#define L_F6B   3936    // 96 f32
#define L_XPAD  4352    // [8][36][38] f32 = 43776 B   (stage -> B)
#define L_S2H   48128   // [8][6][16][18] f16 = 27648 B (B -> C builds)
#define L_AI    4352    // [288][56] f16 = 32256 B      (C, overlays XPAD)
#define L_S4    48128   // [8][16][40] f16 = 10240 B    (C-epi -> A5 build, overlays S2H)
#define L_A5    4352    // [32][520] f16 = 33280 B      (D, overlays AI)
#define L_A6    37632   // [32][136] f16 = 8704 B       (D-epi -> E)
#define L_HB    48128   // [32][88] f32 = 11264 B       (E-epi -> F, overlays S4)
#define LDS_TOTAL 75776

__device__ const unsigned char MASK16[16] = {7,14,28,56,49,35,15,30,60,57,51,39,27,54,45,63};

__device__ __forceinline__ float squash(float x) {
    float z = (2.0f / 3.0f) * x;
    float a = fabsf(z);
    float e = __expf(-2.0f * a);
    float t = (1.0f - e) * __builtin_amdgcn_rcpf(1.0f + e);
    return copysignf(1.7159f * t, z);
}

__global__ __launch_bounds__(256) void prep_kernel(
    const float* __restrict__ c1_w, const float* __restrict__ c1_b,
    const float* __restrict__ s2_w, const float* __restrict__ s2_b,
    const float* __restrict__ c3_w, const float* __restrict__ c3_b,
    const float* __restrict__ s4_w, const float* __restrict__ s4_b,
    const float* __restrict__ c5_w, const float* __restrict__ f6_w,
    float* __restrict__ ws)
{
    const int gid = blockIdx.x * 256 + threadIdx.x;
    const int gstr = gridDim.x * 256;
    // folded C1+S2 kernel
    for (int idx = gid; idx < 216; idx += gstr) {
        int c = idx / 36, r = idx - c * 36;
        int u = r / 6, v = r - u * 6;
        float s = 0.f;
        #pragma unroll
        for (int dy = 0; dy < 2; ++dy)
            #pragma unroll
            for (int dx = 0; dx < 2; ++dx) {
                int ky = u - dy, kx = v - dx;
                if (ky >= 0 && ky < 5 && kx >= 0 && kx < 5)
                    s += c1_w[(c * 5 + ky) * 5 + kx];
            }
        ws[WS_K1 + idx] = 0.25f * s * s2_w[c];
    }
    if (gid < 6)  ws[WS_B1 + gid] = s2_w[gid] * c1_b[gid] + s2_b[gid];
    if (gid < 16) ws[WS_B3 + gid] = s4_w[gid] * c3_b[gid] + s4_b[gid];
    // W3H: [6 i][16 n][48 k] f16, folded+masked C3+S4
    h16* W3H = (h16*)(ws + WS_W3H);
    for (int idx = gid; idx < 4608; idx += gstr) {
        int i = idx / 768, r = idx - i * 768;
        int n = r / 48, k = r - n * 48;
        float val = 0.f;
        if (k < 36) {
            int u = k / 6, v = k - u * 6;
            float s = 0.f;
            #pragma unroll
            for (int dy = 0; dy < 2; ++dy)
                #pragma unroll
                for (int dx = 0; dx < 2; ++dx) {
                    int ky = u - dy, kx = v - dx;
                    if (ky >= 0 && ky < 5 && kx >= 0 && kx < 5)
                        s += c3_w[((n * 6 + i) * 5 + ky) * 5 + kx];
                }
            val = ((MASK16[n] >> i) & 1) ? 0.25f * s4_w[n] * s : 0.f;
        }
        W3H[idx] = (h16)val;
    }
    // W5H: [16 i][128 n][32 k] f16
    h16* W5H = (h16*)(ws + WS_W5H);
    for (int idx = gid; idx < 65536; idx += gstr) {
        int i = idx >> 12, r = idx & 4095;
        int n = r >> 5, k = r & 31;
        float val = (n < 120 && k < 25) ? c5_w[n * 400 + i * 25 + k] : 0.f;
        W5H[idx] = (h16)val;
    }
    // F6H: [96 n][128 k] f16
    h16* F6H = (h16*)(ws + WS_F6H);
    for (int idx = gid; idx < 12288; idx += gstr) {
        int n = idx >> 7, k = idx & 127;
        float val = (n < 84 && k < 120) ? f6_w[n * 120 + k] : 0.f;
        F6H[idx] = (h16)val;
    }
}

__global__ __launch_bounds__(256) void lenet_kernel(
    const float* __restrict__ x,
    const float* __restrict__ c5_b, const float* __restrict__ f6_b,
    const float* __restrict__ rbf_w,
    const float* __restrict__ ws,
    float* __restrict__ out)
{
    __shared__ __align__(16) char smem[LDS_TOTAL];
    float* s_rbf = (float*)(smem + L_RBF);
    float* s_b3  = (float*)(smem + L_B3);
    float* s_c5b = (float*)(smem + L_C5B);
    float* s_f6b = (float*)(smem + L_F6B);
    float* XPAD  = (float*)(smem + L_XPAD);
    h16*  S2H    = (h16*)(smem + L_S2H);
    h16*  AI     = (h16*)(smem + L_AI);
    h16*  S4     = (h16*)(smem + L_S4);
    h16*  A5     = (h16*)(smem + L_A5);
    h16*  A6     = (h16*)(smem + L_A6);
    float* HB    = (float*)(smem + L_HB);

    const int tid  = threadIdx.x;
    const int wave = __builtin_amdgcn_readfirstlane(tid >> 6);
    const int lane = tid & 63;
    const int quad = lane >> 4;
    const int lr   = lane & 15;

    // ---- stage constants + input (replicate pad, f32, pitch 38) ----
    for (int idx = tid; idx < 840; idx += 256) {
        int k = idx / 10, c = idx - k * 10;
        s_rbf[c * 84 + k] = rbf_w[idx];
    }
    if (tid < 16)  s_b3[tid] = ws[WS_B3 + tid];
    if (tid < 128) s_c5b[tid] = (tid < 120) ? c5_b[tid] : 0.f;
    if (tid < 96)  s_f6b[tid] = (tid < 84) ? f6_b[tid] : 0.f;
    const float* xb = x + (size_t)blockIdx.x * 8192;
    for (int idx = tid; idx < 10944; idx += 256) {
        int img = idx / 1368, r2 = idx - img * 1368;
        int u = r2 / 38, v = r2 - u * 38;
        if (v > 35) v = 35;
        int sy = min(max(u - 2, 0), 31);
        int sx = min(max(v - 2, 0), 31);
        XPAD[idx] = xb[img * 1024 + sy * 32 + sx];
    }
    __syncthreads();

    // ======== B: C1+S2+act (VALU, SGPR weights) -> S2H f16 ========
    {
        int py = tid >> 4, px = tid & 15;
        #pragma unroll 2
        for (int img = 0; img < 8; ++img) {
            const float* basep = XPAD + img * 1368 + (2 * py) * 38 + 2 * px;
            float win[36];
            #pragma unroll
            for (int u = 0; u < 6; ++u) {
                float2 a0 = *(const float2*)(basep + u * 38);
                float2 a1 = *(const float2*)(basep + u * 38 + 2);
                float2 a2 = *(const float2*)(basep + u * 38 + 4);
                win[u*6+0]=a0.x; win[u*6+1]=a0.y; win[u*6+2]=a1.x;
                win[u*6+3]=a1.y; win[u*6+4]=a2.x; win[u*6+5]=a2.y;
            }
            #pragma unroll
            for (int c = 0; c < 6; ++c) {
                float acc = ws[WS_B1 + c];
                #pragma unroll
                for (int j = 0; j < 36; ++j) acc += win[j] * ws[WS_K1 + c * 36 + j];
                S2H[img * 1728 + c * 288 + py * 18 + px] = (h16)squash(acc);
            }
        }
    }
    __syncthreads();

    // ======== C: C3+S4 via MFMA. GEMM [288 x 6*48] x [6*48 x 16] ========
    {
        const h16* W3H = (const h16*)(ws + WS_W3H);
        h8v w3a[6]; h4v w3b[6];
        #pragma unroll
        for (int i = 0; i < 6; ++i) {
            const h16* bbase = W3H + i * 768 + lr * 48;
            w3a[i] = *(const h8v*)(bbase + quad * 8);
            w3b[i] = *(const h4v*)(bbase + 32 + quad * 4);
        }
        f4v cacc[5] = {};
        for (int i = 0; i < 6; ++i) {
            // build AI [288][56]: row m=(img*36+pos), k=u*6+v from S2H window
            for (int t = tid; t < 8064; t += 256) {
                int row = t / 28, j = t - row * 28;
                h16* dst = AI + row * 56;
                if (j < 18) {
                    int u = j / 3, vv = (j - u * 3) * 2;
                    int img = row / 36, pos = row - img * 36;
                    int py = pos / 6, px = pos - py * 6;
                    unsigned int val = *(const unsigned int*)
                        (S2H + img * 1728 + i * 288 + (2 * py + u) * 18 + 2 * px + vv);
                    *(unsigned int*)(dst + u * 6 + vv) = val;
                } else {
                    *(unsigned int*)(dst + 36 + (j - 18) * 2) = 0u;
                }
            }
            __syncthreads();
            #pragma unroll
            for (int s = 0; s < 5; ++s) {
                int Mt = wave + 4 * s;
                if (Mt < 18) {
                    const h16* ar = AI + (Mt * 16 + lr) * 56;
                    h8v a8 = *(const h8v*)(ar + quad * 8);
                    cacc[s] = __builtin_amdgcn_mfma_f32_16x16x32_f16(a8, w3a[i], cacc[s], 0, 0, 0);
                    h4v a4 = *(const h4v*)(ar + 32 + quad * 4);
                    cacc[s] = __builtin_amdgcn_mfma_f32_16x16x16f16(a4, w3b[i], cacc[s], 0, 0, 0);
                }
            }
            __syncthreads();
        }
        // epilogue: squash -> S4 [8][16][40] (overlays S2H; safe, S2H dead)
        #pragma unroll
        for (int s = 0; s < 5; ++s) {
            int Mt = wave + 4 * s;
            if (Mt < 18) {
                #pragma unroll
                for (int r = 0; r < 4; ++r) {
                    int m = Mt * 16 + quad * 4 + r;
                    int img = m / 36, pos = m - img * 36;
                    float v = cacc[s][r] + s_b3[lr];
                    S4[img * 640 + lr * 40 + pos] = (h16)squash(v);
                }
            }
        }
    }
    __syncthreads();

    // ======== D: C5 via MFMA. GEMM [32 x 512] x [512 x 128] ========
    {
        // build A5 [32][520]: m=img*4+q, k=i*32+(r*5+c)
        for (int t = tid; t < 16384; t += 256) {
            int k = t & 31, i = (t >> 5) & 15, m = t >> 9;
            h16 v = (h16)0.f;
            if (k < 25) {
                int r = k / 5, c = k - r * 5;
                int img = m >> 2, q = m & 3, qy = q >> 1, qx = q & 1;
                v = S4[img * 640 + i * 40 + (qy + r) * 6 + qx + c];
            }
            A5[m * 520 + i * 32 + k] = v;
        }
        __syncthreads();
        const h16* W5H = (const h16*)(ws + WS_W5H);
        f4v dacc[2][2] = {};
        #pragma unroll 4
        for (int i = 0; i < 16; ++i) {
            h8v bf0 = *(const h8v*)(W5H + i * 4096 + (wave * 32 + lr) * 32 + quad * 8);
            h8v bf1 = *(const h8v*)(W5H + i * 4096 + (wave * 32 + 16 + lr) * 32 + quad * 8);
            h8v af0 = *(const h8v*)(A5 + lr * 520 + i * 32 + quad * 8);
            h8v af1 = *(const h8v*)(A5 + (16 + lr) * 520 + i * 32 + quad * 8);
            dacc[0][0] = __builtin_amdgcn_mfma_f32_16x16x32_f16(af0, bf0, dacc[0][0], 0, 0, 0);
            dacc[0][1] = __builtin_amdgcn_mfma_f32_16x16x32_f16(af0, bf1, dacc[0][1], 0, 0, 0);
            dacc[1][0] = __builtin_amdgcn_mfma_f32_16x16x32_f16(af1, bf0, dacc[1][0], 0, 0, 0);
            dacc[1][1] = __builtin_amdgcn_mfma_f32_16x16x32_f16(af1, bf1, dacc[1][1], 0, 0, 0);
        }
        // zero pad cols 120..127 of A6
        if (tid < 256) {
            int m = tid >> 3, c = 120 + (tid & 7);
            A6[m * 136 + c] = (h16)0.f;
        }
        // epilogue with reference reshape mapping: row=img*4+(n/30), col=(n%30)*4+q
        #pragma unroll
        for (int mt = 0; mt < 2; ++mt)
            #pragma unroll
            for (int nt = 0; nt < 2; ++nt) {
                int n = wave * 32 + nt * 16 + lr;
                if (n < 120) {
                    int tt = n / 30, cb = (n - tt * 30) * 4;
                    float bias = s_c5b[n];
                    #pragma unroll
                    for (int r = 0; r < 4; ++r) {
                        int m = mt * 16 + quad * 4 + r;
                        int img = m >> 2, q = m & 3;
                        A6[(img * 4 + tt) * 136 + cb + q] = (h16)(dacc[mt][nt][r] + bias);
                    }
                }
            }
    }
    __syncthreads();

    // ======== E: F6+act via MFMA. GEMM [32 x 128] x [128 x 96] ========
    {
        const h16* F6H = (const h16*)(ws + WS_F6H);
        int Mt = wave >> 1, nb = (wave & 1) * 3;
        f4v eacc[3] = {};
        #pragma unroll
        for (int kc = 0; kc < 4; ++kc) {
            h8v a8 = *(const h8v*)(A6 + (Mt * 16 + lr) * 136 + kc * 32 + quad * 8);
            #pragma unroll
            for (int j = 0; j < 3; ++j) {
                int n = (nb + j) * 16 + lr;
                h8v b8 = *(const h8v*)(F6H + n * 128 + kc * 32 + quad * 8);
                eacc[j] = __builtin_amdgcn_mfma_f32_16x16x32_f16(a8, b8, eacc[j], 0, 0, 0);
            }
        }
        #pragma unroll
        for (int j = 0; j < 3; ++j) {
            int n = (nb + j) * 16 + lr;
            if (n < 84) {
                float bias = s_f6b[n];
                #pragma unroll
                for (int r = 0; r < 4; ++r) {
                    int m = Mt * 16 + quad * 4 + r;
                    HB[m * 88 + n] = squash(eacc[j][r] + bias);
                }
            }
        }
    }
    __syncthreads();

    // ======== F: RBF distances (VALU) ========
    for (int t = tid; t < 320; t += 256) {
        int m = t / 10, cls = t - m * 10;
        const float4* hr = (const float4*)(HB + m * 88);
        const float4* pr = (const float4*)(s_rbf + cls * 84);
        float a = 0.f;
        #pragma unroll
        for (int u = 0; u < 21; ++u) {
            float4 hv = hr[u], pv = pr[u];
            float dx = hv.x - pv.x, dy = hv.y - pv.y;
            float dz = hv.z - pv.z, dw = hv.w - pv.w;
            a += dx * dx + dy * dy + dz * dz + dw * dw;
        }
        out[(size_t)blockIdx.x * 320 + t] = a;
    }
}

extern "C" void kernel_launch(void* const* d_in, const int* in_sizes, int n_in,
                              void* d_out, int out_size, void* d_ws, size_t ws_size,
                              hipStream_t stream) {
    (void)n_in; (void)out_size; (void)ws_size;
    const float* x     = (const float*)d_in[0];
    const float* c1_w  = (const float*)d_in[1];
    const float* c1_b  = (const float*)d_in[2];
    const float* s2_w  = (const float*)d_in[3];
    const float* s2_b  = (const float*)d_in[4];
    const float* c3_w  = (const float*)d_in[5];
    const float* c3_b  = (const float*)d_in[6];
    const float* s4_w  = (const float*)d_in[7];
    const float* s4_b  = (const float*)d_in[8];
    const float* c5_w  = (const float*)d_in[9];
    const float* c5_b  = (const float*)d_in[10];
    const float* f6_w  = (const float*)d_in[11];
    const float* f6_b  = (const float*)d_in[12];
    const float* rbf_w = (const float*)d_in[13];
    float* out = (float*)d_out;
    float* ws  = (float*)d_ws;

    const int B = in_sizes[0] / 1024;   // 8192

    prep_kernel<<<64, 256, 0, stream>>>(c1_w, c1_b, s2_w, s2_b, c3_w, c3_b,
                                        s4_w, s4_b, c5_w, f6_w, ws);
    lenet_kernel<<<B / 8, 256, 0, stream>>>(x, c5_b, f6_b, rbf_w, ws, out);
}

// Round 5
// 210.850 us; speedup vs baseline: 5.2592x; 1.2629x over previous
//
#include <hip/hip_runtime.h>
#include <math.h>

// LeNet-5 fused forward, G=4 images per 256-thread block, 2048 blocks, f16 MFMA.
typedef _Float16 h16;
typedef h16  h8v __attribute__((ext_vector_type(8)));
typedef h16  h4v __attribute__((ext_vector_type(4)));
typedef float f4v __attribute__((ext_vector_type(4)));

// ws float offsets
#define WS_K1   0       // 216 f32: folded C1+S2 6x6x6
#define WS_B1   216     // 6 f32
#define WS_B3   224     // 16 f32
#define WS_W3H  240     // 2304 f32 = [6][16][48] f16 (C3 B^T, k=u*6+v, pad 36..47=0)
#define WS_W5H  2544    // 32768 f32 = [16][128][32] f16 (C5 B^T, k=r*5+c, pads 0)
#define WS_F6H  35312   // 6144 f32 = [96][128] f16 (F6 B^T, pads 0)

// LDS byte offsets (unions)
#define L_RBF   0       // 840 f32 transposed [10][84]
#define L_B3    3360    // 16 f32
#define L_C5B   3424    // 128 f32
#define L_F6B   3936    // 96 f32
#define L_S2H   4352    // [4][6][16][18] f16 = 13824 B (B -> C builds)       ends 18176
#define L_XPAD  18176   // [4][36][38] f32 = 21888 B    (stage -> B)          ends 40064
#define L_AI    18176   // [144][56] f16 = 16128 B      (C, overlays XPAD)    ends 34304
#define L_A5    18176   // [16][520] f16 = 16640 B      (D, overlays AI)      ends 34816
#define L_S4    34816   // [4][16][40] f16 = 5120 B     (C-epi -> A5 build)   ends 39936
#define L_A6    4352    // [16][136] f16 = 4352 B       (D-epi -> E, over S2H) ends 8704
#define L_HB    8704    // [16][88] f32 = 5632 B        (E-epi -> F)          ends 14336
#define LDS_TOTAL 40064

__device__ const unsigned char MASK16[16] = {7,14,28,56,49,35,15,30,60,57,51,39,27,54,45,63};

__device__ __forceinline__ float squash(float x) {
    float z = (2.0f / 3.0f) * x;
    float a = fabsf(z);
    float e = __expf(-2.0f * a);
    float t = (1.0f - e) * __builtin_amdgcn_rcpf(1.0f + e);
    return copysignf(1.7159f * t, z);
}

__global__ __launch_bounds__(256) void prep_kernel(
    const float* __restrict__ c1_w, const float* __restrict__ c1_b,
    const float* __restrict__ s2_w, const float* __restrict__ s2_b,
    const float* __restrict__ c3_w, const float* __restrict__ c3_b,
    const float* __restrict__ s4_w, const float* __restrict__ s4_b,
    const float* __restrict__ c5_w, const float* __restrict__ f6_w,
    float* __restrict__ ws)
{
    const int gid = blockIdx.x * 256 + threadIdx.x;
    const int gstr = gridDim.x * 256;
    for (int idx = gid; idx < 216; idx += gstr) {
        int c = idx / 36, r = idx - c * 36;
        int u = r / 6, v = r - u * 6;
        float s = 0.f;
        #pragma unroll
        for (int dy = 0; dy < 2; ++dy)
            #pragma unroll
            for (int dx = 0; dx < 2; ++dx) {
                int ky = u - dy, kx = v - dx;
                if (ky >= 0 && ky < 5 && kx >= 0 && kx < 5)
                    s += c1_w[(c * 5 + ky) * 5 + kx];
            }
        ws[WS_K1 + idx] = 0.25f * s * s2_w[c];
    }
    if (gid < 6)  ws[WS_B1 + gid] = s2_w[gid] * c1_b[gid] + s2_b[gid];
    if (gid < 16) ws[WS_B3 + gid] = s4_w[gid] * c3_b[gid] + s4_b[gid];
    h16* W3H = (h16*)(ws + WS_W3H);
    for (int idx = gid; idx < 4608; idx += gstr) {
        int i = idx / 768, r = idx - i * 768;
        int n = r / 48, k = r - n * 48;
        float val = 0.f;
        if (k < 36) {
            int u = k / 6, v = k - u * 6;
            float s = 0.f;
            #pragma unroll
            for (int dy = 0; dy < 2; ++dy)
                #pragma unroll
                for (int dx = 0; dx < 2; ++dx) {
                    int ky = u - dy, kx = v - dx;
                    if (ky >= 0 && ky < 5 && kx >= 0 && kx < 5)
                        s += c3_w[((n * 6 + i) * 5 + ky) * 5 + kx];
                }
            val = ((MASK16[n] >> i) & 1) ? 0.25f * s4_w[n] * s : 0.f;
        }
        W3H[idx] = (h16)val;
    }
    h16* W5H = (h16*)(ws + WS_W5H);
    for (int idx = gid; idx < 65536; idx += gstr) {
        int i = idx >> 12, r = idx & 4095;
        int n = r >> 5, k = r & 31;
        float val = (n < 120 && k < 25) ? c5_w[n * 400 + i * 25 + k] : 0.f;
        W5H[idx] = (h16)val;
    }
    h16* F6H = (h16*)(ws + WS_F6H);
    for (int idx = gid; idx < 12288; idx += gstr) {
        int n = idx >> 7, k = idx & 127;
        float val = (n < 84 && k < 120) ? f6_w[n * 120 + k] : 0.f;
        F6H[idx] = (h16)val;
    }
}

__global__ __launch_bounds__(256, 4) void lenet_kernel(
    const float* __restrict__ x,
    const float* __restrict__ c5_b, const float* __restrict__ f6_b,
    const float* __restrict__ rbf_w,
    const float* __restrict__ ws,
    float* __restrict__ out)
{
    __shared__ __align__(16) char smem[LDS_TOTAL];
    float* s_rbf = (float*)(smem + L_RBF);
    float* s_b3  = (float*)(smem + L_B3);
    float* s_c5b = (float*)(smem + L_C5B);
    float* s_f6b = (float*)(smem + L_F6B);
    float* XPAD  = (float*)(smem + L_XPAD);
    h16*  S2H    = (h16*)(smem + L_S2H);
    h16*  AI     = (h16*)(smem + L_AI);
    h16*  S4     = (h16*)(smem + L_S4);
    h16*  A5     = (h16*)(smem + L_A5);
    h16*  A6     = (h16*)(smem + L_A6);
    float* HB    = (float*)(smem + L_HB);

    const int tid  = threadIdx.x;
    const int wave = __builtin_amdgcn_readfirstlane(tid >> 6);
    const int lane = tid & 63;
    const int quad = lane >> 4;
    const int lr   = lane & 15;

    // ---- stage constants + input (replicate pad, f32, pitch 38) ----
    for (int idx = tid; idx < 840; idx += 256) {
        int k = idx / 10, c = idx - k * 10;
        s_rbf[c * 84 + k] = rbf_w[idx];
    }
    if (tid < 16)  s_b3[tid] = ws[WS_B3 + tid];
    if (tid < 128) s_c5b[tid] = (tid < 120) ? c5_b[tid] : 0.f;
    if (tid < 96)  s_f6b[tid] = (tid < 84) ? f6_b[tid] : 0.f;
    const float* xb = x + (size_t)blockIdx.x * 4096;
    for (int idx = tid; idx < 5472; idx += 256) {
        int img = idx / 1368, r2 = idx - img * 1368;
        int u = r2 / 38, v = r2 - u * 38;
        if (v > 35) v = 35;
        int sy = min(max(u - 2, 0), 31);
        int sx = min(max(v - 2, 0), 31);
        XPAD[idx] = xb[img * 1024 + sy * 32 + sx];
    }
    __syncthreads();

    // ======== B: C1+S2+act (VALU, SGPR weights) -> S2H f16 ========
    {
        int py = tid >> 4, px = tid & 15;
        #pragma unroll 2
        for (int img = 0; img < 4; ++img) {
            const float* basep = XPAD + img * 1368 + (2 * py) * 38 + 2 * px;
            float win[36];
            #pragma unroll
            for (int u = 0; u < 6; ++u) {
                float2 a0 = *(const float2*)(basep + u * 38);
                float2 a1 = *(const float2*)(basep + u * 38 + 2);
                float2 a2 = *(const float2*)(basep + u * 38 + 4);
                win[u*6+0]=a0.x; win[u*6+1]=a0.y; win[u*6+2]=a1.x;
                win[u*6+3]=a1.y; win[u*6+4]=a2.x; win[u*6+5]=a2.y;
            }
            #pragma unroll
            for (int c = 0; c < 6; ++c) {
                float acc = ws[WS_B1 + c];
                #pragma unroll
                for (int j = 0; j < 36; ++j) acc += win[j] * ws[WS_K1 + c * 36 + j];
                S2H[img * 1728 + c * 288 + py * 18 + px] = (h16)squash(acc);
            }
        }
    }
    __syncthreads();

    // ======== C: C3+S4 via MFMA. GEMM [144 x 6*48] x [6*48 x 16] ========
    {
        const h16* W3H = (const h16*)(ws + WS_W3H);
        h8v w3a[6]; h4v w3b[6];
        #pragma unroll
        for (int i = 0; i < 6; ++i) {
            const h16* bbase = W3H + i * 768 + lr * 48;
            w3a[i] = *(const h8v*)(bbase + quad * 8);
            w3b[i] = *(const h4v*)(bbase + 32 + quad * 4);
        }
        f4v cacc[3] = {};
        for (int i = 0; i < 6; ++i) {
            // build AI [144][56]: row m=(img*36+pos), k=u*6+v from S2H window
            for (int t = tid; t < 4032; t += 256) {
                int row = t / 28, j = t - row * 28;
                h16* dst = AI + row * 56;
                if (j < 18) {
                    int u = j / 3, vv = (j - u * 3) * 2;
                    int img = row / 36, pos = row - img * 36;
                    int py = pos / 6, px = pos - py * 6;
                    unsigned int val = *(const unsigned int*)
                        (S2H + img * 1728 + i * 288 + (2 * py + u) * 18 + 2 * px + vv);
                    *(unsigned int*)(dst + u * 6 + vv) = val;
                } else {
                    *(unsigned int*)(dst + 36 + (j - 18) * 2) = 0u;
                }
            }
            __syncthreads();
            #pragma unroll
            for (int s = 0; s < 3; ++s) {
                int Mt = wave + 4 * s;
                if (Mt < 9) {
                    const h16* ar = AI + (Mt * 16 + lr) * 56;
                    h8v a8 = *(const h8v*)(ar + quad * 8);
                    cacc[s] = __builtin_amdgcn_mfma_f32_16x16x32_f16(a8, w3a[i], cacc[s], 0, 0, 0);
                    h4v a4 = *(const h4v*)(ar + 32 + quad * 4);
                    cacc[s] = __builtin_amdgcn_mfma_f32_16x16x16f16(a4, w3b[i], cacc[s], 0, 0, 0);
                }
            }
            __syncthreads();
        }
        // epilogue: squash -> S4 [4][16][40]
        #pragma unroll
        for (int s = 0; s < 3; ++s) {
            int Mt = wave + 4 * s;
            if (Mt < 9) {
                #pragma unroll
                for (int r = 0; r < 4; ++r) {
                    int m = Mt * 16 + quad * 4 + r;
                    int img = m / 36, pos = m - img * 36;
                    float v = cacc[s][r] + s_b3[lr];
                    S4[img * 640 + lr * 40 + pos] = (h16)squash(v);
                }
            }
        }
    }
    __syncthreads();

    // ======== D: C5 via MFMA. GEMM [16 x 512] x [512 x 128] ========
    {
        // build A5 [16][520]: m=img*4+q, k=i*32+(r*5+c)
        for (int t = tid; t < 8192; t += 256) {
            int k = t & 31, i = (t >> 5) & 15, m = t >> 9;
            h16 v = (h16)0.f;
            if (k < 25) {
                int r = k / 5, c = k - r * 5;
                int img = m >> 2, q = m & 3, qy = q >> 1, qx = q & 1;
                v = S4[img * 640 + i * 40 + (qy + r) * 6 + qx + c];
            }
            A5[m * 520 + i * 32 + k] = v;
        }
        __syncthreads();
        const h16* W5H = (const h16*)(ws + WS_W5H);
        f4v dacc[2] = {};
        #pragma unroll 4
        for (int i = 0; i < 16; ++i) {
            h8v bf0 = *(const h8v*)(W5H + i * 4096 + (wave * 32 + lr) * 32 + quad * 8);
            h8v bf1 = *(const h8v*)(W5H + i * 4096 + (wave * 32 + 16 + lr) * 32 + quad * 8);
            h8v af0 = *(const h8v*)(A5 + lr * 520 + i * 32 + quad * 8);
            dacc[0] = __builtin_amdgcn_mfma_f32_16x16x32_f16(af0, bf0, dacc[0], 0, 0, 0);
            dacc[1] = __builtin_amdgcn_mfma_f32_16x16x32_f16(af0, bf1, dacc[1], 0, 0, 0);
        }
        // zero pad cols 120..127 of A6
        if (tid < 128) {
            int m = tid >> 3, c = 120 + (tid & 7);
            A6[m * 136 + c] = (h16)0.f;
        }
        // epilogue, reference reshape: row=img*4+(n/30), col=(n%30)*4+q
        #pragma unroll
        for (int nt = 0; nt < 2; ++nt) {
            int n = wave * 32 + nt * 16 + lr;
            if (n < 120) {
                int tt = n / 30, cb = (n - tt * 30) * 4;
                float bias = s_c5b[n];
                #pragma unroll
                for (int r = 0; r < 4; ++r) {
                    int m = quad * 4 + r;
                    int img = m >> 2, q = m & 3;
                    A6[(img * 4 + tt) * 136 + cb + q] = (h16)(dacc[nt][r] + bias);
                }
            }
        }
    }
    __syncthreads();

    // ======== E: F6+act via MFMA. GEMM [16 x 128] x [128 x 96] ========
    {
        const h16* F6H = (const h16*)(ws + WS_F6H);
        f4v eacc[2] = {};
        #pragma unroll
        for (int kc = 0; kc < 4; ++kc) {
            h8v a8 = *(const h8v*)(A6 + lr * 136 + kc * 32 + quad * 8);
            h8v b0 = *(const h8v*)(F6H + (wave * 16 + lr) * 128 + kc * 32 + quad * 8);
            eacc[0] = __builtin_amdgcn_mfma_f32_16x16x32_f16(a8, b0, eacc[0], 0, 0, 0);
            if (wave < 2) {
                h8v b1 = *(const h8v*)(F6H + ((wave + 4) * 16 + lr) * 128 + kc * 32 + quad * 8);
                eacc[1] = __builtin_amdgcn_mfma_f32_16x16x32_f16(a8, b1, eacc[1], 0, 0, 0);
            }
        }
        {
            int n = wave * 16 + lr;   // 0..63, always < 84
            float bias = s_f6b[n];
            #pragma unroll
            for (int r = 0; r < 4; ++r) {
                int m = quad * 4 + r;
                HB[m * 88 + n] = squash(eacc[0][r] + bias);
            }
        }
        if (wave < 2) {
            int n = (wave + 4) * 16 + lr;  // 64..95
            if (n < 84) {
                float bias = s_f6b[n];
                #pragma unroll
                for (int r = 0; r < 4; ++r) {
                    int m = quad * 4 + r;
                    HB[m * 88 + n] = squash(eacc[1][r] + bias);
                }
            }
        }
    }
    __syncthreads();

    // ======== F: RBF distances (VALU) ========
    if (tid < 160) {
        int m = tid / 10, cls = tid - m * 10;
        const float4* hr = (const float4*)(HB + m * 88);
        const float4* pr = (const float4*)(s_rbf + cls * 84);
        float a = 0.f;
        #pragma unroll
        for (int u = 0; u < 21; ++u) {
            float4 hv = hr[u], pv = pr[u];
            float dx = hv.x - pv.x, dy = hv.y - pv.y;
            float dz = hv.z - pv.z, dw = hv.w - pv.w;
            a += dx * dx + dy * dy + dz * dz + dw * dw;
        }
        out[(size_t)blockIdx.x * 160 + tid] = a;
    }
}

extern "C" void kernel_launch(void* const* d_in, const int* in_sizes, int n_in,
                              void* d_out, int out_size, void* d_ws, size_t ws_size,
                              hipStream_t stream) {
    (void)n_in; (void)out_size; (void)ws_size;
    const float* x     = (const float*)d_in[0];
    const float* c1_w  = (const float*)d_in[1];
    const float* c1_b  = (const float*)d_in[2];
    const float* s2_w  = (const float*)d_in[3];
    const float* s2_b  = (const float*)d_in[4];
    const float* c3_w  = (const float*)d_in[5];
    const float* c3_b  = (const float*)d_in[6];
    const float* s4_w  = (const float*)d_in[7];
    const float* s4_b  = (const float*)d_in[8];
    const float* c5_w  = (const float*)d_in[9];
    const float* c5_b  = (const float*)d_in[10];
    const float* f6_w  = (const float*)d_in[11];
    const float* f6_b  = (const float*)d_in[12];
    const float* rbf_w = (const float*)d_in[13];
    float* out = (float*)d_out;
    float* ws  = (float*)d_ws;

    const int B = in_sizes[0] / 1024;   // 8192

    prep_kernel<<<64, 256, 0, stream>>>(c1_w, c1_b, s2_w, s2_b, c3_w, c3_b,
                                        s4_w, s4_b, c5_w, f6_w, ws);
    lenet_kernel<<<B / 4, 256, 0, stream>>>(x, c5_b, f6_b, rbf_w, ws, out);
}

// Round 6
// 196.188 us; speedup vs baseline: 5.6522x; 1.0747x over previous
//
#include <hip/hip_runtime.h>
#include <math.h>

// LeNet-5 fused forward, G=4 images per 256-thread block, 2048 blocks, f16 MFMA + fdot2.
typedef _Float16 h16;
typedef h16  h8v __attribute__((ext_vector_type(8)));
typedef h16  h4v __attribute__((ext_vector_type(4)));
typedef h16  h2v __attribute__((ext_vector_type(2)));
typedef float f4v __attribute__((ext_vector_type(4)));

#if defined(__has_builtin)
#if __has_builtin(__builtin_amdgcn_fdot2)
#define FDOT2(a,b,c) __builtin_amdgcn_fdot2((a),(b),(c),false)
#endif
#endif
#ifndef FDOT2
#define FDOT2(a,b,c) ((c) + (float)(a).x*(float)(b).x + (float)(a).y*(float)(b).y)
#endif

// ws float offsets
#define WS_K1H  0       // 216 h16 = 108 f32: folded C1+S2 6x6x6 packed f16 pairs
#define WS_B1   216     // 6 f32
#define WS_B3   224     // 16 f32
#define WS_W3H  240     // 2304 f32 = [6][16][48] f16 (C3 B^T, k=u*6+v, pad 36..47=0)
#define WS_W5H  2544    // 32768 f32 = [16][128][32] f16 (C5 B^T, k=r*5+c, pads 0)
#define WS_F6H  35312   // 6144 f32 = [96][128] f16 (F6 B^T, pads 0)

// LDS byte offsets (unions)
#define L_RBF   0       // 840 f32 transposed [10][84]
#define L_B3    3360    // 16 f32
#define L_C5B   3424    // 128 f32
#define L_F6B   3936    // 96 f32
#define L_S2H   4352    // [4][6][16][18] f16 = 13824 B (B -> C)            ends 18176
#define L_A6    4352    // [16][136] f16 = 4352 B  (D-epi -> E, over S2H)   ends 8704
#define L_HB    8704    // [16][88] f32 = 5632 B   (E-epi -> F, over S2H)   ends 14336
#define L_XPADH 18176   // [4][36][40] f16 = 11520 B (stage -> B)           ends 29696
#define L_AI    18176   // [144][56] f16 = 16128 B (C, over XPADH)          ends 34304
#define L_A5    18176   // [16][520] f16 = 16640 B (D, over AI)             ends 34816
#define L_S4    34816   // [4][16][40] f16 = 5120 B (C-epi -> A5 build)     ends 39936
#define LDS_TOTAL 39936

__device__ const unsigned char MASK16[16] = {7,14,28,56,49,35,15,30,60,57,51,39,27,54,45,63};

__device__ __forceinline__ float squash(float x) {
    float z = (2.0f / 3.0f) * x;
    float a = fabsf(z);
    float e = __expf(-2.0f * a);
    float t = (1.0f - e) * __builtin_amdgcn_rcpf(1.0f + e);
    return copysignf(1.7159f * t, z);
}

__global__ __launch_bounds__(256) void prep_kernel(
    const float* __restrict__ c1_w, const float* __restrict__ c1_b,
    const float* __restrict__ s2_w, const float* __restrict__ s2_b,
    const float* __restrict__ c3_w, const float* __restrict__ c3_b,
    const float* __restrict__ s4_w, const float* __restrict__ s4_b,
    const float* __restrict__ c5_w, const float* __restrict__ f6_w,
    float* __restrict__ ws)
{
    const int gid = blockIdx.x * 256 + threadIdx.x;
    const int gstr = gridDim.x * 256;
    h16* K1H = (h16*)ws;
    for (int idx = gid; idx < 216; idx += gstr) {
        int c = idx / 36, r = idx - c * 36;
        int u = r / 6, v = r - u * 6;
        float s = 0.f;
        #pragma unroll
        for (int dy = 0; dy < 2; ++dy)
            #pragma unroll
            for (int dx = 0; dx < 2; ++dx) {
                int ky = u - dy, kx = v - dx;
                if (ky >= 0 && ky < 5 && kx >= 0 && kx < 5)
                    s += c1_w[(c * 5 + ky) * 5 + kx];
            }
        K1H[idx] = (h16)(0.25f * s * s2_w[c]);
    }
    if (gid < 6)  ws[WS_B1 + gid] = s2_w[gid] * c1_b[gid] + s2_b[gid];
    if (gid < 16) ws[WS_B3 + gid] = s4_w[gid] * c3_b[gid] + s4_b[gid];
    h16* W3H = (h16*)(ws + WS_W3H);
    for (int idx = gid; idx < 4608; idx += gstr) {
        int i = idx / 768, r = idx - i * 768;
        int n = r / 48, k = r - n * 48;
        float val = 0.f;
        if (k < 36) {
            int u = k / 6, v = k - u * 6;
            float s = 0.f;
            #pragma unroll
            for (int dy = 0; dy < 2; ++dy)
                #pragma unroll
                for (int dx = 0; dx < 2; ++dx) {
                    int ky = u - dy, kx = v - dx;
                    if (ky >= 0 && ky < 5 && kx >= 0 && kx < 5)
                        s += c3_w[((n * 6 + i) * 5 + ky) * 5 + kx];
                }
            val = ((MASK16[n] >> i) & 1) ? 0.25f * s4_w[n] * s : 0.f;
        }
        W3H[idx] = (h16)val;
    }
    h16* W5H = (h16*)(ws + WS_W5H);
    for (int idx = gid; idx < 65536; idx += gstr) {
        int i = idx >> 12, r = idx & 4095;
        int n = r >> 5, k = r & 31;
        float val = (n < 120 && k < 25) ? c5_w[n * 400 + i * 25 + k] : 0.f;
        W5H[idx] = (h16)val;
    }
    h16* F6H = (h16*)(ws + WS_F6H);
    for (int idx = gid; idx < 12288; idx += gstr) {
        int n = idx >> 7, k = idx & 127;
        float val = (n < 84 && k < 120) ? f6_w[n * 120 + k] : 0.f;
        F6H[idx] = (h16)val;
    }
}

__global__ __launch_bounds__(256, 4) void lenet_kernel(
    const float* __restrict__ x,
    const float* __restrict__ c5_b, const float* __restrict__ f6_b,
    const float* __restrict__ rbf_w,
    const float* __restrict__ ws,
    float* __restrict__ out)
{
    __shared__ __align__(16) char smem[LDS_TOTAL];
    float* s_rbf = (float*)(smem + L_RBF);
    float* s_b3  = (float*)(smem + L_B3);
    float* s_c5b = (float*)(smem + L_C5B);
    float* s_f6b = (float*)(smem + L_F6B);
    h16*  XPADH  = (h16*)(smem + L_XPADH);
    h16*  S2H    = (h16*)(smem + L_S2H);
    h16*  AI     = (h16*)(smem + L_AI);
    h16*  S4     = (h16*)(smem + L_S4);
    h16*  A5     = (h16*)(smem + L_A5);
    h16*  A6     = (h16*)(smem + L_A6);
    float* HB    = (float*)(smem + L_HB);

    const int tid  = threadIdx.x;
    const int wave = __builtin_amdgcn_readfirstlane(tid >> 6);
    const int lane = tid & 63;
    const int quad = lane >> 4;
    const int lr   = lane & 15;

    // ---- stage constants + input (replicate pad, f16 packed pairs, pitch 40) ----
    for (int idx = tid; idx < 840; idx += 256) {
        int k = idx / 10, c = idx - k * 10;
        s_rbf[c * 84 + k] = rbf_w[idx];
    }
    if (tid < 16)  s_b3[tid] = ws[WS_B3 + tid];
    if (tid < 128) s_c5b[tid] = (tid < 120) ? c5_b[tid] : 0.f;
    if (tid < 96)  s_f6b[tid] = (tid < 84) ? f6_b[tid] : 0.f;
    const float* xb = x + (size_t)blockIdx.x * 4096;
    for (int idx = tid; idx < 2880; idx += 256) {
        int img = idx / 720, r2 = idx - img * 720;
        int u = r2 / 20, v2 = r2 - u * 20;
        int sy = min(max(u - 2, 0), 31);
        int c0 = min(max(2 * v2 - 2, 0), 31);
        int c1 = min(max(2 * v2 - 1, 0), 31);
        const float* xr = xb + img * 1024 + sy * 32;
        h2v hv; hv.x = (h16)xr[c0]; hv.y = (h16)xr[c1];
        *(h2v*)(XPADH + img * 1440 + u * 40 + 2 * v2) = hv;
    }
    __syncthreads();

    // ======== B: C1+S2+act via fdot2 (f16 inputs, f32 acc) -> S2H f16 ========
    {
        int py = tid >> 4, px = tid & 15;
        h2v win2[4][18];
        #pragma unroll
        for (int img = 0; img < 4; ++img) {
            const h16* basep = XPADH + img * 1440 + (2 * py) * 40 + 2 * px;
            #pragma unroll
            for (int u = 0; u < 6; ++u)
                #pragma unroll
                for (int p = 0; p < 3; ++p)
                    win2[img][u * 3 + p] = *(const h2v*)(basep + u * 40 + 2 * p);
        }
        const h2v* K1H = (const h2v*)ws;  // [6][18]
        #pragma unroll
        for (int c = 0; c < 6; ++c) {
            float bias = ws[WS_B1 + c];
            h2v wv[18];
            #pragma unroll
            for (int j = 0; j < 18; ++j) wv[j] = K1H[c * 18 + j];
            #pragma unroll
            for (int img = 0; img < 4; ++img) {
                float acc = bias;
                #pragma unroll
                for (int j = 0; j < 18; ++j)
                    acc = FDOT2(win2[img][j], wv[j], acc);
                S2H[img * 1728 + c * 288 + py * 18 + px] = (h16)squash(acc);
            }
        }
    }
    __syncthreads();

    // ======== C: C3+S4 via MFMA. GEMM [144 x 6*48] x [6*48 x 16] ========
    {
        const h16* W3H = (const h16*)(ws + WS_W3H);
        h8v w3a[6]; h4v w3b[6];
        #pragma unroll
        for (int i = 0; i < 6; ++i) {
            const h16* bbase = W3H + i * 768 + lr * 48;
            w3a[i] = *(const h8v*)(bbase + quad * 8);
            w3b[i] = *(const h4v*)(bbase + 32 + quad * 4);
        }
        f4v cacc[3] = {};
        for (int i = 0; i < 6; ++i) {
            // build AI [144][56]: row m=(img*36+pos), k=u*6+v from S2H window
            for (int t = tid; t < 4032; t += 256) {
                int row = t / 28, j = t - row * 28;
                h16* dst = AI + row * 56;
                if (j < 18) {
                    int u = j / 3, vv = (j - u * 3) * 2;
                    int img = row / 36, pos = row - img * 36;
                    int py = pos / 6, px = pos - py * 6;
                    unsigned int val = *(const unsigned int*)
                        (S2H + img * 1728 + i * 288 + (2 * py + u) * 18 + 2 * px + vv);
                    *(unsigned int*)(dst + u * 6 + vv) = val;
                } else {
                    *(unsigned int*)(dst + 36 + (j - 18) * 2) = 0u;
                }
            }
            __syncthreads();
            #pragma unroll
            for (int s = 0; s < 3; ++s) {
                int Mt = wave + 4 * s;
                if (Mt < 9) {
                    const h16* ar = AI + (Mt * 16 + lr) * 56;
                    h8v a8 = *(const h8v*)(ar + quad * 8);
                    cacc[s] = __builtin_amdgcn_mfma_f32_16x16x32_f16(a8, w3a[i], cacc[s], 0, 0, 0);
                    h4v a4 = *(const h4v*)(ar + 32 + quad * 4);
                    cacc[s] = __builtin_amdgcn_mfma_f32_16x16x16f16(a4, w3b[i], cacc[s], 0, 0, 0);
                }
            }
            __syncthreads();
        }
        // epilogue: squash -> S4 [4][16][40]
        #pragma unroll
        for (int s = 0; s < 3; ++s) {
            int Mt = wave + 4 * s;
            if (Mt < 9) {
                #pragma unroll
                for (int r = 0; r < 4; ++r) {
                    int m = Mt * 16 + quad * 4 + r;
                    int img = m / 36, pos = m - img * 36;
                    float v = cacc[s][r] + s_b3[lr];
                    S4[img * 640 + lr * 40 + pos] = (h16)squash(v);
                }
            }
        }
    }
    __syncthreads();

    // ======== D: C5 via MFMA. GEMM [16 x 512] x [512 x 128] ========
    {
        // build A5 [16][520]: m=img*4+q, k=i*32+(r*5+c)
        for (int t = tid; t < 8192; t += 256) {
            int k = t & 31, i = (t >> 5) & 15, m = t >> 9;
            h16 v = (h16)0.f;
            if (k < 25) {
                int r = k / 5, c = k - r * 5;
                int img = m >> 2, q = m & 3, qy = q >> 1, qx = q & 1;
                v = S4[img * 640 + i * 40 + (qy + r) * 6 + qx + c];
            }
            A5[m * 520 + i * 32 + k] = v;
        }
        __syncthreads();
        const h16* W5H = (const h16*)(ws + WS_W5H);
        f4v dacc[2] = {};
        #pragma unroll 4
        for (int i = 0; i < 16; ++i) {
            h8v bf0 = *(const h8v*)(W5H + i * 4096 + (wave * 32 + lr) * 32 + quad * 8);
            h8v bf1 = *(const h8v*)(W5H + i * 4096 + (wave * 32 + 16 + lr) * 32 + quad * 8);
            h8v af0 = *(const h8v*)(A5 + lr * 520 + i * 32 + quad * 8);
            dacc[0] = __builtin_amdgcn_mfma_f32_16x16x32_f16(af0, bf0, dacc[0], 0, 0, 0);
            dacc[1] = __builtin_amdgcn_mfma_f32_16x16x32_f16(af0, bf1, dacc[1], 0, 0, 0);
        }
        // zero pad cols 120..127 of A6
        if (tid < 128) {
            int m = tid >> 3, c = 120 + (tid & 7);
            A6[m * 136 + c] = (h16)0.f;
        }
        // epilogue, reference reshape: row=img*4+(n/30), col=(n%30)*4+q
        #pragma unroll
        for (int nt = 0; nt < 2; ++nt) {
            int n = wave * 32 + nt * 16 + lr;
            if (n < 120) {
                int tt = n / 30, cb = (n - tt * 30) * 4;
                float bias = s_c5b[n];
                #pragma unroll
                for (int r = 0; r < 4; ++r) {
                    int m = quad * 4 + r;
                    int img = m >> 2, q = m & 3;
                    A6[(img * 4 + tt) * 136 + cb + q] = (h16)(dacc[nt][r] + bias);
                }
            }
        }
    }
    __syncthreads();

    // ======== E: F6+act via MFMA. GEMM [16 x 128] x [128 x 96] ========
    {
        const h16* F6H = (const h16*)(ws + WS_F6H);
        f4v eacc[2] = {};
        #pragma unroll
        for (int kc = 0; kc < 4; ++kc) {
            h8v a8 = *(const h8v*)(A6 + lr * 136 + kc * 32 + quad * 8);
            h8v b0 = *(const h8v*)(F6H + (wave * 16 + lr) * 128 + kc * 32 + quad * 8);
            eacc[0] = __builtin_amdgcn_mfma_f32_16x16x32_f16(a8, b0, eacc[0], 0, 0, 0);
            if (wave < 2) {
                h8v b1 = *(const h8v*)(F6H + ((wave + 4) * 16 + lr) * 128 + kc * 32 + quad * 8);
                eacc[1] = __builtin_amdgcn_mfma_f32_16x16x32_f16(a8, b1, eacc[1], 0, 0, 0);
            }
        }
        {
            int n = wave * 16 + lr;   // 0..63 < 84
            float bias = s_f6b[n];
            #pragma unroll
            for (int r = 0; r < 4; ++r) {
                int m = quad * 4 + r;
                HB[m * 88 + n] = squash(eacc[0][r] + bias);
            }
        }
        if (wave < 2) {
            int n = (wave + 4) * 16 + lr;  // 64..95
            if (n < 84) {
                float bias = s_f6b[n];
                #pragma unroll
                for (int r = 0; r < 4; ++r) {
                    int m = quad * 4 + r;
                    HB[m * 88 + n] = squash(eacc[1][r] + bias);
                }
            }
        }
    }
    __syncthreads();

    // ======== F: RBF distances (VALU) ========
    if (tid < 160) {
        int m = tid / 10, cls = tid - m * 10;
        const float4* hr = (const float4*)(HB + m * 88);
        const float4* pr = (const float4*)(s_rbf + cls * 84);
        float a = 0.f;
        #pragma unroll
        for (int u = 0; u < 21; ++u) {
            float4 hv = hr[u], pv = pr[u];
            float dx = hv.x - pv.x, dy = hv.y - pv.y;
            float dz = hv.z - pv.z, dw = hv.w - pv.w;
            a += dx * dx + dy * dy + dz * dz + dw * dw;
        }
        out[(size_t)blockIdx.x * 160 + tid] = a;
    }
}

extern "C" void kernel_launch(void* const* d_in, const int* in_sizes, int n_in,
                              void* d_out, int out_size, void* d_ws, size_t ws_size,
                              hipStream_t stream) {
    (void)n_in; (void)out_size; (void)ws_size;
    const float* x     = (const float*)d_in[0];
    const float* c1_w  = (const float*)d_in[1];
    const float* c1_b  = (const float*)d_in[2];
    const float* s2_w  = (const float*)d_in[3];
    const float* s2_b  = (const float*)d_in[4];
    const float* c3_w  = (const float*)d_in[5];
    const float* c3_b  = (const float*)d_in[6];
    const float* s4_w  = (const float*)d_in[7];
    const float* s4_b  = (const float*)d_in[8];
    const float* c5_w  = (const float*)d_in[9];
    const float* c5_b  = (const float*)d_in[10];
    const float* f6_w  = (const float*)d_in[11];
    const float* f6_b  = (const float*)d_in[12];
    const float* rbf_w = (const float*)d_in[13];
    float* out = (float*)d_out;
    float* ws  = (float*)d_ws;

    const int B = in_sizes[0] / 1024;   // 8192

    prep_kernel<<<256, 256, 0, stream>>>(c1_w, c1_b, s2_w, s2_b, c3_w, c3_b,
                                         s4_w, s4_b, c5_w, f6_w, ws);
    lenet_kernel<<<B / 4, 256, 0, stream>>>(x, c5_b, f6_b, rbf_w, ws, out);
}

// Round 7
// 160.476 us; speedup vs baseline: 6.9100x; 1.2225x over previous
//
#include <hip/hip_runtime.h>
#include <math.h>

// LeNet-5 fused forward, G=4 images per 256-thread block, 2048 blocks, f16 MFMA + fdot2.
typedef _Float16 h16;
typedef h16  h8v __attribute__((ext_vector_type(8)));
typedef h16  h4v __attribute__((ext_vector_type(4)));
typedef h16  h2v __attribute__((ext_vector_type(2)));
typedef float f4v __attribute__((ext_vector_type(4)));

#if defined(__has_builtin)
#if __has_builtin(__builtin_amdgcn_fdot2)
#define FDOT2(a,b,c) __builtin_amdgcn_fdot2((a),(b),(c),false)
#endif
#endif
#ifndef FDOT2
#define FDOT2(a,b,c) ((c) + (float)(a).x*(float)(b).x + (float)(a).y*(float)(b).y)
#endif

// ws float offsets
#define WS_K1H  0       // 216 h16 = 108 f32: folded C1+S2 6x6x6 packed f16 pairs
#define WS_B1   216     // 6 f32
#define WS_B3   224     // 16 f32
#define WS_W3H  240     // 2304 f32 = [6][16][48] f16 (C3 B^T, k=u*6+v, pad 36..47=0)
#define WS_W5H  2544    // 32768 f32 = [16][128][32] f16 (C5 B^T, k=r*5+c, pads 0)
#define WS_F6H  35312   // 6144 f32 = [96][128] f16 (F6 B^T, pads 0)

// LDS byte offsets (unions)
#define L_RBF   0       // 840 f32 transposed [10][84]
#define L_B3    3360    // 16 f32
#define L_C5B   3424    // 128 f32
#define L_F6B   3936    // 96 f32
#define L_S2H   4352    // [4][6][16][18] f16 = 13824 B (B -> C)            ends 18176
#define L_A6    4352    // [16][136] f16 = 4352 B  (D-epi -> E, over S2H)   ends 8704
#define L_HB    8704    // [16][88] f32 = 5632 B   (E-epi -> F, over S2H)   ends 14336
#define L_XPADH 18176   // [4][36][40] f16 = 11520 B (stage -> B)           ends 29696
#define L_AI    18176   // [144][56] f16 = 16128 B (C, over XPADH)          ends 34304
#define L_A5    18176   // [16][520] f16 = 16640 B (D, over AI)             ends 34816
#define L_S4    34816   // [4][16][40] f16 = 5120 B (C-epi -> A5 build)     ends 39936
#define LDS_TOTAL 39936

__device__ const unsigned char MASK16[16] = {7,14,28,56,49,35,15,30,60,57,51,39,27,54,45,63};

__device__ __forceinline__ float squash(float x) {
    float z = (2.0f / 3.0f) * x;
    float a = fabsf(z);
    float e = __expf(-2.0f * a);
    float t = (1.0f - e) * __builtin_amdgcn_rcpf(1.0f + e);
    return copysignf(1.7159f * t, z);
}

__global__ __launch_bounds__(256) void prep_kernel(
    const float* __restrict__ c1_w, const float* __restrict__ c1_b,
    const float* __restrict__ s2_w, const float* __restrict__ s2_b,
    const float* __restrict__ c3_w, const float* __restrict__ c3_b,
    const float* __restrict__ s4_w, const float* __restrict__ s4_b,
    const float* __restrict__ c5_w, const float* __restrict__ f6_w,
    float* __restrict__ ws)
{
    const int gid = blockIdx.x * 256 + threadIdx.x;
    const int gstr = gridDim.x * 256;
    h16* K1H = (h16*)ws;
    for (int idx = gid; idx < 216; idx += gstr) {
        int c = idx / 36, r = idx - c * 36;
        int u = r / 6, v = r - u * 6;
        float s = 0.f;
        #pragma unroll
        for (int dy = 0; dy < 2; ++dy)
            #pragma unroll
            for (int dx = 0; dx < 2; ++dx) {
                int ky = u - dy, kx = v - dx;
                if (ky >= 0 && ky < 5 && kx >= 0 && kx < 5)
                    s += c1_w[(c * 5 + ky) * 5 + kx];
            }
        K1H[idx] = (h16)(0.25f * s * s2_w[c]);
    }
    if (gid < 6)  ws[WS_B1 + gid] = s2_w[gid] * c1_b[gid] + s2_b[gid];
    if (gid < 16) ws[WS_B3 + gid] = s4_w[gid] * c3_b[gid] + s4_b[gid];
    h16* W3H = (h16*)(ws + WS_W3H);
    for (int idx = gid; idx < 4608; idx += gstr) {
        int i = idx / 768, r = idx - i * 768;
        int n = r / 48, k = r - n * 48;
        float val = 0.f;
        if (k < 36) {
            int u = k / 6, v = k - u * 6;
            float s = 0.f;
            #pragma unroll
            for (int dy = 0; dy < 2; ++dy)
                #pragma unroll
                for (int dx = 0; dx < 2; ++dx) {
                    int ky = u - dy, kx = v - dx;
                    if (ky >= 0 && ky < 5 && kx >= 0 && kx < 5)
                        s += c3_w[((n * 6 + i) * 5 + ky) * 5 + kx];
                }
            val = ((MASK16[n] >> i) & 1) ? 0.25f * s4_w[n] * s : 0.f;
        }
        W3H[idx] = (h16)val;
    }
    h16* W5H = (h16*)(ws + WS_W5H);
    for (int idx = gid; idx < 65536; idx += gstr) {
        int i = idx >> 12, r = idx & 4095;
        int n = r >> 5, k = r & 31;
        float val = (n < 120 && k < 25) ? c5_w[n * 400 + i * 25 + k] : 0.f;
        W5H[idx] = (h16)val;
    }
    h16* F6H = (h16*)(ws + WS_F6H);
    for (int idx = gid; idx < 12288; idx += gstr) {
        int n = idx >> 7, k = idx & 127;
        float val = (n < 84 && k < 120) ? f6_w[n * 120 + k] : 0.f;
        F6H[idx] = (h16)val;
    }
}

__global__ __launch_bounds__(256, 4) void lenet_kernel(
    const float* __restrict__ x,
    const float* __restrict__ c5_b, const float* __restrict__ f6_b,
    const float* __restrict__ rbf_w,
    const float* __restrict__ ws,
    float* __restrict__ out)
{
    __shared__ __align__(16) char smem[LDS_TOTAL];
    float* s_rbf = (float*)(smem + L_RBF);
    float* s_b3  = (float*)(smem + L_B3);
    float* s_c5b = (float*)(smem + L_C5B);
    float* s_f6b = (float*)(smem + L_F6B);
    h16*  XPADH  = (h16*)(smem + L_XPADH);
    h16*  S2H    = (h16*)(smem + L_S2H);
    h16*  AI     = (h16*)(smem + L_AI);
    h16*  S4     = (h16*)(smem + L_S4);
    h16*  A5     = (h16*)(smem + L_A5);
    h16*  A6     = (h16*)(smem + L_A6);
    float* HB    = (float*)(smem + L_HB);

    const int tid  = threadIdx.x;
    const int wave = __builtin_amdgcn_readfirstlane(tid >> 6);
    const int lane = tid & 63;
    const int quad = lane >> 4;
    const int lr   = lane & 15;

    // ---- stage constants + input (replicate pad, f16 packed pairs, pitch 40) ----
    for (int idx = tid; idx < 840; idx += 256) {
        int k = idx / 10, c = idx - k * 10;
        s_rbf[c * 84 + k] = rbf_w[idx];
    }
    if (tid < 16)  s_b3[tid] = ws[WS_B3 + tid];
    if (tid < 128) s_c5b[tid] = (tid < 120) ? c5_b[tid] : 0.f;
    if (tid < 96)  s_f6b[tid] = (tid < 84) ? f6_b[tid] : 0.f;
    const float* xb = x + (size_t)blockIdx.x * 4096;
    for (int idx = tid; idx < 2880; idx += 256) {
        int img = idx / 720, r2 = idx - img * 720;
        int u = r2 / 20, v2 = r2 - u * 20;
        int sy = min(max(u - 2, 0), 31);
        int c0 = min(max(2 * v2 - 2, 0), 31);
        int c1 = min(max(2 * v2 - 1, 0), 31);
        const float* xr = xb + img * 1024 + sy * 32;
        h2v hv; hv.x = (h16)xr[c0]; hv.y = (h16)xr[c1];
        *(h2v*)(XPADH + img * 1440 + u * 40 + 2 * v2) = hv;
    }
    __syncthreads();

    // ======== B: C1+S2+act via fdot2 (f16 inputs, f32 acc) -> S2H f16 ========
    {
        int py = tid >> 4, px = tid & 15;
        h2v win2[4][18];
        #pragma unroll
        for (int img = 0; img < 4; ++img) {
            const h16* basep = XPADH + img * 1440 + (2 * py) * 40 + 2 * px;
            #pragma unroll
            for (int u = 0; u < 6; ++u)
                #pragma unroll
                for (int p = 0; p < 3; ++p)
                    win2[img][u * 3 + p] = *(const h2v*)(basep + u * 40 + 2 * p);
        }
        const h2v* K1H = (const h2v*)ws;  // [6][18]
        #pragma unroll
        for (int c = 0; c < 6; ++c) {
            float bias = ws[WS_B1 + c];
            h2v wv[18];
            #pragma unroll
            for (int j = 0; j < 18; ++j) wv[j] = K1H[c * 18 + j];
            #pragma unroll
            for (int img = 0; img < 4; ++img) {
                float acc = bias;
                #pragma unroll
                for (int j = 0; j < 18; ++j)
                    acc = FDOT2(win2[img][j], wv[j], acc);
                S2H[img * 1728 + c * 288 + py * 18 + px] = (h16)squash(acc);
            }
        }
    }
    __syncthreads();

    // ======== C: C3+S4 via MFMA. GEMM [144 x 6*48] x [6*48 x 16] ========
    {
        const h16* W3H = (const h16*)(ws + WS_W3H);
        h8v w3a[6]; h4v w3b[6];
        #pragma unroll
        for (int i = 0; i < 6; ++i) {
            const h16* bbase = W3H + i * 768 + lr * 48;
            w3a[i] = *(const h8v*)(bbase + quad * 8);
            w3b[i] = *(const h4v*)(bbase + 32 + quad * 4);
        }
        // pre-zero AI pad cols 36..55 once (XPADH dead after post-B barrier)
        for (int t = tid; t < 1440; t += 256) {
            int row = t / 10, j = t - row * 10;
            *(unsigned int*)(AI + row * 56 + 36 + 2 * j) = 0u;
        }
        // per-thread row geometry for im2col (row = tid, valid < 144)
        const int rowv = (tid < 144) ? tid : 0;
        const int imgR = rowv / 36, posR = rowv - imgR * 36;
        const int pyR = posR / 6, pxR = posR - pyR * 6;
        const h16* srcR = S2H + imgR * 1728 + (2 * pyR) * 18 + 2 * pxR;
        h16* dstR = AI + rowv * 56;
        f4v cacc[3] = {};
        for (int i = 0; i < 6; ++i) {
            // build AI [144][56]: one row per thread, fully unrolled
            if (tid < 144) {
                const h16* src = srcR + i * 288;
                #pragma unroll
                for (int u = 0; u < 6; ++u) {
                    *(unsigned int*)(dstR + u * 6)     = *(const unsigned int*)(src + u * 18);
                    *(unsigned int*)(dstR + u * 6 + 2) = *(const unsigned int*)(src + u * 18 + 2);
                    *(unsigned int*)(dstR + u * 6 + 4) = *(const unsigned int*)(src + u * 18 + 4);
                }
            }
            __syncthreads();
            #pragma unroll
            for (int s = 0; s < 3; ++s) {
                int Mt = wave + 4 * s;
                if (Mt < 9) {
                    const h16* ar = AI + (Mt * 16 + lr) * 56;
                    h8v a8 = *(const h8v*)(ar + quad * 8);
                    cacc[s] = __builtin_amdgcn_mfma_f32_16x16x32_f16(a8, w3a[i], cacc[s], 0, 0, 0);
                    h4v a4 = *(const h4v*)(ar + 32 + quad * 4);
                    cacc[s] = __builtin_amdgcn_mfma_f32_16x16x16f16(a4, w3b[i], cacc[s], 0, 0, 0);
                }
            }
            if (i < 5) __syncthreads();   // last one covered by post-phase barrier
        }
        // epilogue: squash -> S4 [4][16][40] (disjoint from AI region)
        #pragma unroll
        for (int s = 0; s < 3; ++s) {
            int Mt = wave + 4 * s;
            if (Mt < 9) {
                #pragma unroll
                for (int r = 0; r < 4; ++r) {
                    int m = Mt * 16 + quad * 4 + r;
                    int img = m / 36, pos = m - img * 36;
                    float v = cacc[s][r] + s_b3[lr];
                    S4[img * 640 + lr * 40 + pos] = (h16)squash(v);
                }
            }
        }
    }
    __syncthreads();

    // ======== D: C5 via MFMA. GEMM [16 x 512] x [512 x 128] ========
    {
        // build A5 [16][520]: m=img*4+q, k=i*32+(r*5+c)
        for (int t = tid; t < 8192; t += 256) {
            int k = t & 31, i = (t >> 5) & 15, m = t >> 9;
            h16 v = (h16)0.f;
            if (k < 25) {
                int r = k / 5, c = k - r * 5;
                int img = m >> 2, q = m & 3, qy = q >> 1, qx = q & 1;
                v = S4[img * 640 + i * 40 + (qy + r) * 6 + qx + c];
            }
            A5[m * 520 + i * 32 + k] = v;
        }
        __syncthreads();
        const h16* W5H = (const h16*)(ws + WS_W5H);
        f4v dacc[2] = {};
        #pragma unroll 4
        for (int i = 0; i < 16; ++i) {
            h8v bf0 = *(const h8v*)(W5H + i * 4096 + (wave * 32 + lr) * 32 + quad * 8);
            h8v bf1 = *(const h8v*)(W5H + i * 4096 + (wave * 32 + 16 + lr) * 32 + quad * 8);
            h8v af0 = *(const h8v*)(A5 + lr * 520 + i * 32 + quad * 8);
            dacc[0] = __builtin_amdgcn_mfma_f32_16x16x32_f16(af0, bf0, dacc[0], 0, 0, 0);
            dacc[1] = __builtin_amdgcn_mfma_f32_16x16x32_f16(af0, bf1, dacc[1], 0, 0, 0);
        }
        // zero pad cols 120..127 of A6
        if (tid < 128) {
            int m = tid >> 3, c = 120 + (tid & 7);
            A6[m * 136 + c] = (h16)0.f;
        }
        // epilogue, reference reshape: row=img*4+(n/30), col=(n%30)*4+q
        #pragma unroll
        for (int nt = 0; nt < 2; ++nt) {
            int n = wave * 32 + nt * 16 + lr;
            if (n < 120) {
                int tt = n / 30, cb = (n - tt * 30) * 4;
                float bias = s_c5b[n];
                #pragma unroll
                for (int r = 0; r < 4; ++r) {
                    int m = quad * 4 + r;
                    int img = m >> 2, q = m & 3;
                    A6[(img * 4 + tt) * 136 + cb + q] = (h16)(dacc[nt][r] + bias);
                }
            }
        }
    }
    __syncthreads();

    // ======== E: F6+act via MFMA. GEMM [16 x 128] x [128 x 96] ========
    {
        const h16* F6H = (const h16*)(ws + WS_F6H);
        f4v eacc[2] = {};
        #pragma unroll
        for (int kc = 0; kc < 4; ++kc) {
            h8v a8 = *(const h8v*)(A6 + lr * 136 + kc * 32 + quad * 8);
            h8v b0 = *(const h8v*)(F6H + (wave * 16 + lr) * 128 + kc * 32 + quad * 8);
            eacc[0] = __builtin_amdgcn_mfma_f32_16x16x32_f16(a8, b0, eacc[0], 0, 0, 0);
            if (wave < 2) {
                h8v b1 = *(const h8v*)(F6H + ((wave + 4) * 16 + lr) * 128 + kc * 32 + quad * 8);
                eacc[1] = __builtin_amdgcn_mfma_f32_16x16x32_f16(a8, b1, eacc[1], 0, 0, 0);
            }
        }
        {
            int n = wave * 16 + lr;   // 0..63 < 84
            float bias = s_f6b[n];
            #pragma unroll
            for (int r = 0; r < 4; ++r) {
                int m = quad * 4 + r;
                HB[m * 88 + n] = squash(eacc[0][r] + bias);
            }
        }
        if (wave < 2) {
            int n = (wave + 4) * 16 + lr;  // 64..95
            if (n < 84) {
                float bias = s_f6b[n];
                #pragma unroll
                for (int r = 0; r < 4; ++r) {
                    int m = quad * 4 + r;
                    HB[m * 88 + n] = squash(eacc[1][r] + bias);
                }
            }
        }
    }
    __syncthreads();

    // ======== F: RBF distances (VALU) ========
    if (tid < 160) {
        int m = tid / 10, cls = tid - m * 10;
        const float4* hr = (const float4*)(HB + m * 88);
        const float4* pr = (const float4*)(s_rbf + cls * 84);
        float a = 0.f;
        #pragma unroll
        for (int u = 0; u < 21; ++u) {
            float4 hv = hr[u], pv = pr[u];
            float dx = hv.x - pv.x, dy = hv.y - pv.y;
            float dz = hv.z - pv.z, dw = hv.w - pv.w;
            a += dx * dx + dy * dy + dz * dz + dw * dw;
        }
        out[(size_t)blockIdx.x * 160 + tid] = a;
    }
}

extern "C" void kernel_launch(void* const* d_in, const int* in_sizes, int n_in,
                              void* d_out, int out_size, void* d_ws, size_t ws_size,
                              hipStream_t stream) {
    (void)n_in; (void)out_size; (void)ws_size;
    const float* x     = (const float*)d_in[0];
    const float* c1_w  = (const float*)d_in[1];
    const float* c1_b  = (const float*)d_in[2];
    const float* s2_w  = (const float*)d_in[3];
    const float* s2_b  = (const float*)d_in[4];
    const float* c3_w  = (const float*)d_in[5];
    const float* c3_b  = (const float*)d_in[6];
    const float* s4_w  = (const float*)d_in[7];
    const float* s4_b  = (const float*)d_in[8];
    const float* c5_w  = (const float*)d_in[9];
    const float* c5_b  = (const float*)d_in[10];
    const float* f6_w  = (const float*)d_in[11];
    const float* f6_b  = (const float*)d_in[12];
    const float* rbf_w = (const float*)d_in[13];
    float* out = (float*)d_out;
    float* ws  = (float*)d_ws;

    const int B = in_sizes[0] / 1024;   // 8192

    prep_kernel<<<256, 256, 0, stream>>>(c1_w, c1_b, s2_w, s2_b, c3_w, c3_b,
                                         s4_w, s4_b, c5_w, f6_w, ws);
    lenet_kernel<<<B / 4, 256, 0, stream>>>(x, c5_b, f6_b, rbf_w, ws, out);
}

// Round 8
// 149.407 us; speedup vs baseline: 7.4220x; 1.0741x over previous
//
#include <hip/hip_runtime.h>
#include <math.h>

// LeNet-5 fused forward, G=4 images per 256-thread block, 2048 blocks, f16 MFMA + fdot2.
typedef _Float16 h16;
typedef h16  h8v __attribute__((ext_vector_type(8)));
typedef h16  h4v __attribute__((ext_vector_type(4)));
typedef h16  h2v __attribute__((ext_vector_type(2)));
typedef float f4v __attribute__((ext_vector_type(4)));
typedef unsigned int u32;
typedef u32  u4v __attribute__((ext_vector_type(4)));
typedef u32  u2v __attribute__((ext_vector_type(2)));

#if defined(__has_builtin)
#if __has_builtin(__builtin_amdgcn_fdot2)
#define FDOT2(a,b,c) __builtin_amdgcn_fdot2((a),(b),(c),false)
#endif
#endif
#ifndef FDOT2
#define FDOT2(a,b,c) ((c) + (float)(a).x*(float)(b).x + (float)(a).y*(float)(b).y)
#endif

// ws float offsets
#define WS_K1H  0       // 216 h16: folded C1+S2 6x6x6 packed f16 pairs
#define WS_B1   216     // 6 f32
#define WS_B3   224     // 16 f32
#define WS_W3H  240     // [6][16][48] f16 (C3 B^T, k=u*6+v, pad 36..47=0)
#define WS_W5H  2544    // [16][128][32] f16 (C5 B^T, k=r*5+c, pads 0)
#define WS_F6H  35312   // [96][128] f16 (F6 B^T, pads 0)
#define WS_RBFT 41456   // 840 f32: rbf transposed [10][84]

// LDS byte offsets. Lifetimes:
//   [0..960)      constants (whole kernel)
//   [960..14784)  S2H (B->C) ; then S4@960 (C-epi->D-build, pitch 42),
//                 A6@6592 (D-epi->E), HB@960 (E-epi->F)
//   [14784..31424) XPADH (stage->B) / AI pitch 56 (C) / A5 pitch 520 (D)
#define L_B3    0       // 16 f32
#define L_C5B   64      // 128 f32
#define L_F6B   576     // 96 f32
#define L_S2H   960     // [4][6][16][18] f16 = 13824 B
#define L_S4    960     // [4][16][42] f16 = 5376 B
#define L_HB    960     // [16][88] f32 = 5632 B
#define L_A6    6592    // [16][136] f16 = 4352 B
#define L_XPADH 14784   // [4][36][40] f16 = 11520 B
#define L_AI    14784   // [144][56] f16 = 16128 B
#define L_A5    14784   // [16][520] f16 = 16640 B
#define LDS_TOTAL 31424

__device__ const unsigned char MASK16[16] = {7,14,28,56,49,35,15,30,60,57,51,39,27,54,45,63};

__device__ __forceinline__ float squash(float x) {
    float z = (2.0f / 3.0f) * x;
    float a = fabsf(z);
    float e = __expf(-2.0f * a);
    float t = (1.0f - e) * __builtin_amdgcn_rcpf(1.0f + e);
    return copysignf(1.7159f * t, z);
}

__global__ __launch_bounds__(256) void prep_kernel(
    const float* __restrict__ c1_w, const float* __restrict__ c1_b,
    const float* __restrict__ s2_w, const float* __restrict__ s2_b,
    const float* __restrict__ c3_w, const float* __restrict__ c3_b,
    const float* __restrict__ s4_w, const float* __restrict__ s4_b,
    const float* __restrict__ c5_w, const float* __restrict__ f6_w,
    const float* __restrict__ rbf_w,
    float* __restrict__ ws)
{
    const int gid = blockIdx.x * 256 + threadIdx.x;
    const int gstr = gridDim.x * 256;
    h16* K1H = (h16*)ws;
    for (int idx = gid; idx < 216; idx += gstr) {
        int c = idx / 36, r = idx - c * 36;
        int u = r / 6, v = r - u * 6;
        float s = 0.f;
        #pragma unroll
        for (int dy = 0; dy < 2; ++dy)
            #pragma unroll
            for (int dx = 0; dx < 2; ++dx) {
                int ky = u - dy, kx = v - dx;
                if (ky >= 0 && ky < 5 && kx >= 0 && kx < 5)
                    s += c1_w[(c * 5 + ky) * 5 + kx];
            }
        K1H[idx] = (h16)(0.25f * s * s2_w[c]);
    }
    if (gid < 6)  ws[WS_B1 + gid] = s2_w[gid] * c1_b[gid] + s2_b[gid];
    if (gid < 16) ws[WS_B3 + gid] = s4_w[gid] * c3_b[gid] + s4_b[gid];
    h16* W3H = (h16*)(ws + WS_W3H);
    for (int idx = gid; idx < 4608; idx += gstr) {
        int i = idx / 768, r = idx - i * 768;
        int n = r / 48, k = r - n * 48;
        float val = 0.f;
        if (k < 36) {
            int u = k / 6, v = k - u * 6;
            float s = 0.f;
            #pragma unroll
            for (int dy = 0; dy < 2; ++dy)
                #pragma unroll
                for (int dx = 0; dx < 2; ++dx) {
                    int ky = u - dy, kx = v - dx;
                    if (ky >= 0 && ky < 5 && kx >= 0 && kx < 5)
                        s += c3_w[((n * 6 + i) * 5 + ky) * 5 + kx];
                }
            val = ((MASK16[n] >> i) & 1) ? 0.25f * s4_w[n] * s : 0.f;
        }
        W3H[idx] = (h16)val;
    }
    h16* W5H = (h16*)(ws + WS_W5H);
    for (int idx = gid; idx < 65536; idx += gstr) {
        int i = idx >> 12, r = idx & 4095;
        int n = r >> 5, k = r & 31;
        float val = (n < 120 && k < 25) ? c5_w[n * 400 + i * 25 + k] : 0.f;
        W5H[idx] = (h16)val;
    }
    h16* F6H = (h16*)(ws + WS_F6H);
    for (int idx = gid; idx < 12288; idx += gstr) {
        int n = idx >> 7, k = idx & 127;
        float val = (n < 84 && k < 120) ? f6_w[n * 120 + k] : 0.f;
        F6H[idx] = (h16)val;
    }
    for (int idx = gid; idx < 840; idx += gstr) {
        int k = idx / 10, c = idx - k * 10;
        ws[WS_RBFT + c * 84 + k] = rbf_w[idx];
    }
}

__global__ __launch_bounds__(256, 5) void lenet_kernel(
    const float* __restrict__ x,
    const float* __restrict__ c5_b, const float* __restrict__ f6_b,
    const float* __restrict__ ws,
    float* __restrict__ out)
{
    __shared__ __align__(16) char smem[LDS_TOTAL];
    float* s_b3  = (float*)(smem + L_B3);
    float* s_c5b = (float*)(smem + L_C5B);
    float* s_f6b = (float*)(smem + L_F6B);
    h16*  XPADH  = (h16*)(smem + L_XPADH);
    h16*  S2H    = (h16*)(smem + L_S2H);
    h16*  AI     = (h16*)(smem + L_AI);
    h16*  S4     = (h16*)(smem + L_S4);
    h16*  A5     = (h16*)(smem + L_A5);
    h16*  A6     = (h16*)(smem + L_A6);
    float* HB    = (float*)(smem + L_HB);

    const int tid  = threadIdx.x;
    const int wave = __builtin_amdgcn_readfirstlane(tid >> 6);
    const int lane = tid & 63;
    const int quad = lane >> 4;
    const int lr   = lane & 15;

    // ---- stage constants + input (replicate pad, f16 packed pairs, pitch 40) ----
    if (tid < 16)  s_b3[tid] = ws[WS_B3 + tid];
    if (tid < 128) s_c5b[tid] = (tid < 120) ? c5_b[tid] : 0.f;
    if (tid < 96)  s_f6b[tid] = (tid < 84) ? f6_b[tid] : 0.f;
    const float* xb = x + (size_t)blockIdx.x * 4096;
    for (int idx = tid; idx < 2880; idx += 256) {
        int img = idx / 720, r2 = idx - img * 720;
        int u = r2 / 20, v2 = r2 - u * 20;
        int sy = min(max(u - 2, 0), 31);
        int c0 = min(max(2 * v2 - 2, 0), 31);
        int c1 = min(max(2 * v2 - 1, 0), 31);
        const float* xr = xb + img * 1024 + sy * 32;
        h2v hv; hv.x = (h16)xr[c0]; hv.y = (h16)xr[c1];
        *(h2v*)(XPADH + img * 1440 + u * 40 + 2 * v2) = hv;
    }
    __syncthreads();

    // ======== B: C1+S2+act via fdot2 (f16 inputs, f32 acc) -> S2H f16 ========
    {
        int py = tid >> 4, px = tid & 15;
        h2v win2[4][18];
        #pragma unroll
        for (int img = 0; img < 4; ++img) {
            const h16* basep = XPADH + img * 1440 + (2 * py) * 40 + 2 * px;
            #pragma unroll
            for (int u = 0; u < 6; ++u)
                #pragma unroll
                for (int p = 0; p < 3; ++p)
                    win2[img][u * 3 + p] = *(const h2v*)(basep + u * 40 + 2 * p);
        }
        const h2v* K1H = (const h2v*)ws;  // [6][18]
        #pragma unroll
        for (int c = 0; c < 6; ++c) {
            float bias = ws[WS_B1 + c];
            h2v wv[18];
            #pragma unroll
            for (int j = 0; j < 18; ++j) wv[j] = K1H[c * 18 + j];
            #pragma unroll
            for (int img = 0; img < 4; ++img) {
                float acc = bias;
                #pragma unroll
                for (int j = 0; j < 18; ++j)
                    acc = FDOT2(win2[img][j], wv[j], acc);
                S2H[img * 1728 + c * 288 + py * 18 + px] = (h16)squash(acc);
            }
        }
    }
    __syncthreads();

    // ======== C: C3+S4 via MFMA. GEMM [144 x 6*48] x [6*48 x 16] ========
    {
        const h16* W3H = (const h16*)(ws + WS_W3H);
        h8v w3a[6]; h4v w3b[6];
        #pragma unroll
        for (int i = 0; i < 6; ++i) {
            const h16* bbase = W3H + i * 768 + lr * 48;
            w3a[i] = *(const h8v*)(bbase + quad * 8);
            w3b[i] = *(const h4v*)(bbase + 32 + quad * 4);
        }
        // pre-zero AI pad cols 36..55 once (XPADH dead after post-B barrier)
        for (int t = tid; t < 1440; t += 256) {
            int row = t / 10, j = t - row * 10;
            *(u32*)(AI + row * 56 + 36 + 2 * j) = 0u;
        }
        // per-thread row geometry for im2col (row = tid, valid < 144)
        const int rowv = (tid < 144) ? tid : 0;
        const int imgR = rowv / 36, posR = rowv - imgR * 36;
        const int pyR = posR / 6, pxR = posR - pyR * 6;
        const h16* srcR = S2H + imgR * 1728 + (2 * pyR) * 18 + 2 * pxR;
        h16* dstR = AI + rowv * 56;
        f4v cacc[3] = {};
        for (int i = 0; i < 6; ++i) {
            // build AI row in regs (18 aligned u32 reads), burst-write 4xb128 + b64
            if (tid < 144) {
                const h16* src = srcR + i * 288;
                u32 wrow[18];
                #pragma unroll
                for (int u = 0; u < 6; ++u) {
                    wrow[u*3+0] = *(const u32*)(src + u * 18);
                    wrow[u*3+1] = *(const u32*)(src + u * 18 + 2);
                    wrow[u*3+2] = *(const u32*)(src + u * 18 + 4);
                }
                *(u4v*)(dstR)      = (u4v){wrow[0],  wrow[1],  wrow[2],  wrow[3]};
                *(u4v*)(dstR + 8)  = (u4v){wrow[4],  wrow[5],  wrow[6],  wrow[7]};
                *(u4v*)(dstR + 16) = (u4v){wrow[8],  wrow[9],  wrow[10], wrow[11]};
                *(u4v*)(dstR + 24) = (u4v){wrow[12], wrow[13], wrow[14], wrow[15]};
                *(u2v*)(dstR + 32) = (u2v){wrow[16], wrow[17]};
            }
            __syncthreads();
            #pragma unroll
            for (int s = 0; s < 3; ++s) {
                int Mt = wave + 4 * s;
                if (Mt < 9) {
                    const h16* ar = AI + (Mt * 16 + lr) * 56;
                    h8v a8 = *(const h8v*)(ar + quad * 8);
                    cacc[s] = __builtin_amdgcn_mfma_f32_16x16x32_f16(a8, w3a[i], cacc[s], 0, 0, 0);
                    h4v a4 = *(const h4v*)(ar + 32 + quad * 4);
                    cacc[s] = __builtin_amdgcn_mfma_f32_16x16x16f16(a4, w3b[i], cacc[s], 0, 0, 0);
                }
            }
            if (i < 5) __syncthreads();
        }
        // epilogue: squash -> S4 [4][16][42] (overlays dead S2H; no reader until post-C barrier)
        #pragma unroll
        for (int s = 0; s < 3; ++s) {
            int Mt = wave + 4 * s;
            if (Mt < 9) {
                #pragma unroll
                for (int r = 0; r < 4; ++r) {
                    int m = Mt * 16 + quad * 4 + r;
                    int img = m / 36, pos = m - img * 36;
                    float v = cacc[s][r] + s_b3[lr];
                    S4[img * 672 + lr * 42 + pos] = (h16)squash(v);
                }
            }
        }
    }
    __syncthreads();

    // ======== D: C5 via MFMA. GEMM [16 x 512] x [512 x 128] ========
    {
        // build A5 [16][520] in ONE round: thread = (m, i); 25 u16 reads -> 4 b128 writes
        {
            int m = tid >> 4, i = tid & 15;
            int img = m >> 2, q = m & 3, qy = q >> 1, qx = q & 1;
            const h16* s4b = S4 + img * 672 + i * 42 + qy * 6 + qx;
            h16* dst = A5 + m * 520 + i * 32;
            #pragma unroll
            for (int c = 0; c < 4; ++c) {
                h8v v;
                #pragma unroll
                for (int j = 0; j < 8; ++j) {
                    int k = c * 8 + j;
                    v[j] = (k < 25) ? s4b[(k / 5) * 6 + (k % 5)] : (h16)0.f;
                }
                *(h8v*)(dst + c * 8) = v;
            }
        }
        __syncthreads();
        const h16* W5H = (const h16*)(ws + WS_W5H);
        f4v dacc[2] = {};
        #pragma unroll 4
        for (int i = 0; i < 16; ++i) {
            h8v bf0 = *(const h8v*)(W5H + i * 4096 + (wave * 32 + lr) * 32 + quad * 8);
            h8v bf1 = *(const h8v*)(W5H + i * 4096 + (wave * 32 + 16 + lr) * 32 + quad * 8);
            h8v af0 = *(const h8v*)(A5 + lr * 520 + i * 32 + quad * 8);
            dacc[0] = __builtin_amdgcn_mfma_f32_16x16x32_f16(af0, bf0, dacc[0], 0, 0, 0);
            dacc[1] = __builtin_amdgcn_mfma_f32_16x16x32_f16(af0, bf1, dacc[1], 0, 0, 0);
        }
        // zero pad cols 120..127 of A6 (u32 writes)
        if (tid < 64) {
            int m = tid >> 2, j = tid & 3;
            *(u32*)(A6 + m * 136 + 120 + 2 * j) = 0u;
        }
        // epilogue, reference reshape: row=img*4+(n/30), col=(n%30)*4+q
        #pragma unroll
        for (int nt = 0; nt < 2; ++nt) {
            int n = wave * 32 + nt * 16 + lr;
            if (n < 120) {
                int tt = n / 30, cb = (n - tt * 30) * 4;
                float bias = s_c5b[n];
                #pragma unroll
                for (int r = 0; r < 4; ++r) {
                    int m = quad * 4 + r;
                    int img = m >> 2, q = m & 3;
                    A6[(img * 4 + tt) * 136 + cb + q] = (h16)(dacc[nt][r] + bias);
                }
            }
        }
    }
    __syncthreads();

    // ======== E: F6+act via MFMA. GEMM [16 x 128] x [128 x 96] ========
    {
        const h16* F6H = (const h16*)(ws + WS_F6H);
        f4v eacc[2] = {};
        #pragma unroll
        for (int kc = 0; kc < 4; ++kc) {
            h8v a8 = *(const h8v*)(A6 + lr * 136 + kc * 32 + quad * 8);
            h8v b0 = *(const h8v*)(F6H + (wave * 16 + lr) * 128 + kc * 32 + quad * 8);
            eacc[0] = __builtin_amdgcn_mfma_f32_16x16x32_f16(a8, b0, eacc[0], 0, 0, 0);
            if (wave < 2) {
                h8v b1 = *(const h8v*)(F6H + ((wave + 4) * 16 + lr) * 128 + kc * 32 + quad * 8);
                eacc[1] = __builtin_amdgcn_mfma_f32_16x16x32_f16(a8, b1, eacc[1], 0, 0, 0);
            }
        }
        {
            int n = wave * 16 + lr;   // 0..63 < 84
            float bias = s_f6b[n];
            #pragma unroll
            for (int r = 0; r < 4; ++r) {
                int m = quad * 4 + r;
                HB[m * 88 + n] = squash(eacc[0][r] + bias);
            }
        }
        if (wave < 2) {
            int n = (wave + 4) * 16 + lr;  // 64..95
            if (n < 84) {
                float bias = s_f6b[n];
                #pragma unroll
                for (int r = 0; r < 4; ++r) {
                    int m = quad * 4 + r;
                    HB[m * 88 + n] = squash(eacc[1][r] + bias);
                }
            }
        }
    }
    __syncthreads();

    // ======== F: RBF distances (VALU); prototypes from L2-resident rbfT ========
    if (tid < 160) {
        int m = tid / 10, cls = tid - m * 10;
        const float4* hr = (const float4*)(HB + m * 88);
        const float4* pr = (const float4*)(ws + WS_RBFT + cls * 84);
        float a = 0.f;
        #pragma unroll
        for (int u = 0; u < 21; ++u) {
            float4 hv = hr[u], pv = pr[u];
            float dx = hv.x - pv.x, dy = hv.y - pv.y;
            float dz = hv.z - pv.z, dw = hv.w - pv.w;
            a += dx * dx + dy * dy + dz * dz + dw * dw;
        }
        out[(size_t)blockIdx.x * 160 + tid] = a;
    }
}

extern "C" void kernel_launch(void* const* d_in, const int* in_sizes, int n_in,
                              void* d_out, int out_size, void* d_ws, size_t ws_size,
                              hipStream_t stream) {
    (void)n_in; (void)out_size; (void)ws_size;
    const float* x     = (const float*)d_in[0];
    const float* c1_w  = (const float*)d_in[1];
    const float* c1_b  = (const float*)d_in[2];
    const float* s2_w  = (const float*)d_in[3];
    const float* s2_b  = (const float*)d_in[4];
    const float* c3_w  = (const float*)d_in[5];
    const float* c3_b  = (const float*)d_in[6];
    const float* s4_w  = (const float*)d_in[7];
    const float* s4_b  = (const float*)d_in[8];
    const float* c5_w  = (const float*)d_in[9];
    const float* c5_b  = (const float*)d_in[10];
    const float* f6_w  = (const float*)d_in[11];
    const float* f6_b  = (const float*)d_in[12];
    const float* rbf_w = (const float*)d_in[13];
    float* out = (float*)d_out;
    float* ws  = (float*)d_ws;

    const int B = in_sizes[0] / 1024;   // 8192

    prep_kernel<<<256, 256, 0, stream>>>(c1_w, c1_b, s2_w, s2_b, c3_w, c3_b,
                                         s4_w, s4_b, c5_w, f6_w, rbf_w, ws);
    lenet_kernel<<<B / 4, 256, 0, stream>>>(x, c5_b, f6_b, ws, out);
}